// Round 3
// baseline (900.074 us; speedup 1.0000x reference)
//
#include <hip/hip_runtime.h>
#include <math.h>

typedef short v8s __attribute__((ext_vector_type(8)));
typedef float v4f __attribute__((ext_vector_type(4)));

__device__ __forceinline__ float b2f(unsigned short u) {
    return __uint_as_float(((unsigned)u) << 16);
}
__device__ __forceinline__ unsigned short f2b(float f) {
    unsigned u = __float_as_uint(f);
    unsigned r = (u + 0x7FFF + ((u >> 16) & 1)) >> 16;
    return (unsigned short)r;
}

// ---------------- zero fill (no hipMemsetAsync needed) ----------------
__global__ __launch_bounds__(256) void zero_fill(float* __restrict__ p, int n) {
    int i = blockIdx.x * 256 + threadIdx.x;
    if (i < n) p[i] = 0.0f;
}

// ---------------- LN row stats from fp32 x: mean & inv-std per row (C=512) ----------------
__global__ __launch_bounds__(256) void ln_stats_kernel(const float* __restrict__ x,
                                                       float2* __restrict__ st) {
    size_t row = blockIdx.x;
    const float2* p = (const float2*)(x + row * 512);
    int t = threadIdx.x;
    float2 v = p[t];
    float s = v.x + v.y, s2 = v.x * v.x + v.y * v.y;
    for (int o = 32; o > 0; o >>= 1) {
        s += __shfl_down(s, o);
        s2 += __shfl_down(s2, o);
    }
    __shared__ float rs[4], rq[4];
    int wave = t >> 6, lane = t & 63;
    if (lane == 0) { rs[wave] = s; rq[wave] = s2; }
    __syncthreads();
    if (t == 0) {
        float ts = rs[0] + rs[1] + rs[2] + rs[3];
        float tq = rq[0] + rq[1] + rq[2] + rq[3];
        float mean = ts * (1.0f / 512.0f);
        float var = tq * (1.0f / 512.0f) - mean * mean;
        st[row] = make_float2(mean, rsqrtf(var + 1e-5f));
    }
}

// ---------------- LayerNorm: bf16 in -> bf16 out, fp32 gamma/beta (LN2) ----------------
__global__ __launch_bounds__(256) void ln_bf16_kernel(const unsigned short* __restrict__ in,
                                                      const float* __restrict__ g,
                                                      const float* __restrict__ bt,
                                                      unsigned short* __restrict__ out) {
    size_t row = blockIdx.x;
    const unsigned short* p = in + row * 512;
    int t = threadIdx.x;
    float v0 = b2f(p[t]);
    float v1 = b2f(p[t + 256]);
    float s = v0 + v1, s2 = v0 * v0 + v1 * v1;
    for (int o = 32; o > 0; o >>= 1) {
        s += __shfl_down(s, o);
        s2 += __shfl_down(s2, o);
    }
    __shared__ float rs[4], rq[4];
    int wave = t >> 6, lane = t & 63;
    if (lane == 0) { rs[wave] = s; rq[wave] = s2; }
    __syncthreads();
    float ts = rs[0] + rs[1] + rs[2] + rs[3];
    float tq = rq[0] + rq[1] + rq[2] + rq[3];
    float mean = ts * (1.0f / 512.0f);
    float var = tq * (1.0f / 512.0f) - mean * mean;
    float inv = rsqrtf(var + 1e-5f);
    unsigned short* o0 = out + row * 512;
    o0[t]       = f2b((v0 - mean) * inv * g[t]       + bt[t]);
    o0[t + 256] = f2b((v1 - mean) * inv * g[t + 256] + bt[t + 256]);
}

// ---------------- weight transpose + fp32->bf16: in [R][C] f32 -> out [C][R] bf16 ----------------
__global__ __launch_bounds__(256) void transpose_f2b(const float* __restrict__ in,
                                                     unsigned short* __restrict__ out,
                                                     int R, int C) {
    __shared__ unsigned short tile[32][33];
    int c0 = blockIdx.x * 32, r0 = blockIdx.y * 32;
    int tx = threadIdx.x, ty = threadIdx.y;
    for (int j = 0; j < 32; j += 8)
        tile[ty + j][tx] = f2b(in[(size_t)(r0 + ty + j) * C + c0 + tx]);
    __syncthreads();
    for (int j = 0; j < 32; j += 8)
        out[(size_t)(c0 + ty + j) * R + r0 + tx] = tile[tx][ty + j];
}

// ---------------- tiled bf16 transpose: in [batch][R][C] -> out [batch][C][R] ----------------
__global__ __launch_bounds__(256) void transpose_bf16(const unsigned short* __restrict__ in,
                                                      unsigned short* __restrict__ out,
                                                      int R, int C) {
    __shared__ unsigned short tile[32][33];
    size_t boff = (size_t)blockIdx.z * R * C;
    int c0 = blockIdx.x * 32, r0 = blockIdx.y * 32;
    int tx = threadIdx.x, ty = threadIdx.y;
    for (int j = 0; j < 32; j += 8)
        tile[ty + j][tx] = in[boff + (size_t)(r0 + ty + j) * C + c0 + tx];
    __syncthreads();
    for (int j = 0; j < 32; j += 8)
        out[boff + (size_t)(c0 + ty + j) * R + r0 + tx] = tile[tx][ty + j];
}

// ---------------- GEMM1, LN fused into A staging; q/k/v slot outputs, relu on q,k ---------------
// x fp32 [32768][512], st per-row (mean,inv), g/b fp32 [512], Bt bf16 [1536][512], bias fp32
__global__ __launch_bounds__(256) void gemm_ln_qkv(const float* __restrict__ x,
                                                   const float2* __restrict__ st,
                                                   const float* __restrict__ g,
                                                   const float* __restrict__ bvec,
                                                   const unsigned short* __restrict__ Bt,
                                                   const float* __restrict__ bias,
                                                   unsigned short* __restrict__ oq,
                                                   unsigned short* __restrict__ ok,
                                                   unsigned short* __restrict__ ov) {
    const int LD = 56;
    __shared__ __align__(16) unsigned short As[128 * LD];
    __shared__ __align__(16) unsigned short Bs[128 * LD];
    int t = threadIdx.x;
    int wave = t >> 6, lane = t & 63;
    int wm = (wave >> 1) * 64, wn = (wave & 1) * 64;
    int m0 = blockIdx.y * 128, n0 = blockIdx.x * 128;
    int mrow = lane & 15, kq = (lane >> 4) * 8;
    v4f acc[4][4] = {};
    int lr = t >> 1;
    int lc0 = (t & 1) * 16;
    float2 mi = st[m0 + lr];
    for (int k0 = 0; k0 < 512; k0 += 32) {
        float xv[16], gv[16], bv[16];
        *(float4*)&xv[0]  = *(const float4*)&x[(size_t)(m0 + lr) * 512 + k0 + lc0];
        *(float4*)&xv[4]  = *(const float4*)&x[(size_t)(m0 + lr) * 512 + k0 + lc0 + 4];
        *(float4*)&xv[8]  = *(const float4*)&x[(size_t)(m0 + lr) * 512 + k0 + lc0 + 8];
        *(float4*)&xv[12] = *(const float4*)&x[(size_t)(m0 + lr) * 512 + k0 + lc0 + 12];
        *(float4*)&gv[0]  = *(const float4*)&g[k0 + lc0];
        *(float4*)&gv[4]  = *(const float4*)&g[k0 + lc0 + 4];
        *(float4*)&gv[8]  = *(const float4*)&g[k0 + lc0 + 8];
        *(float4*)&gv[12] = *(const float4*)&g[k0 + lc0 + 12];
        *(float4*)&bv[0]  = *(const float4*)&bvec[k0 + lc0];
        *(float4*)&bv[4]  = *(const float4*)&bvec[k0 + lc0 + 4];
        *(float4*)&bv[8]  = *(const float4*)&bvec[k0 + lc0 + 8];
        *(float4*)&bv[12] = *(const float4*)&bvec[k0 + lc0 + 12];
        v8s wv0 = *(const v8s*)&Bt[(size_t)(n0 + lr) * 512 + k0 + lc0];
        v8s wv1 = *(const v8s*)&Bt[(size_t)(n0 + lr) * 512 + k0 + lc0 + 8];
        v8s na0, na1;
#pragma unroll
        for (int j = 0; j < 8; j++) {
            na0[j] = (short)f2b((xv[j]     - mi.x) * mi.y * gv[j]     + bv[j]);
            na1[j] = (short)f2b((xv[j + 8] - mi.x) * mi.y * gv[j + 8] + bv[j + 8]);
        }
        __syncthreads();
        *(v8s*)&As[lr * LD + lc0] = na0;
        *(v8s*)&As[lr * LD + lc0 + 8] = na1;
        *(v8s*)&Bs[lr * LD + lc0] = wv0;
        *(v8s*)&Bs[lr * LD + lc0 + 8] = wv1;
        __syncthreads();
        v8s af[4], bf[4];
#pragma unroll
        for (int i = 0; i < 4; i++) af[i] = *(v8s*)&As[(wm + i * 16 + mrow) * LD + kq];
#pragma unroll
        for (int i = 0; i < 4; i++) bf[i] = *(v8s*)&Bs[(wn + i * 16 + mrow) * LD + kq];
#pragma unroll
        for (int i = 0; i < 4; i++)
#pragma unroll
            for (int j = 0; j < 4; j++)
                acc[i][j] = __builtin_amdgcn_mfma_f32_16x16x32_bf16(af[i], bf[j], acc[i][j], 0, 0, 0);
    }
#pragma unroll
    for (int j = 0; j < 4; j++) {
        int col = n0 + wn + j * 16 + mrow;
        float bv = bias[col];
        int seg = col >> 9;
        int c = col & 511;
        unsigned short* base = (seg == 0) ? oq : ((seg == 1) ? ok : ov);
        bool doRelu = col < 1024;
#pragma unroll
        for (int i = 0; i < 4; i++) {
            int row = m0 + wm + i * 16 + (lane >> 4) * 4;
#pragma unroll
            for (int r = 0; r < 4; r++) {
                float v = acc[i][j][r] + bv;
                if (doRelu) v = fmaxf(v, 0.0f);
                base[(size_t)(row + r) * 512 + c] = f2b(v);
            }
        }
    }
}

// ---------------- GEMM2: bf16 A[32768][512] * Bt bf16[512][512] + fp32 bias -> bf16 out ---------
__global__ __launch_bounds__(256) void gemm_bf16(const unsigned short* __restrict__ A,
                                                 const unsigned short* __restrict__ Bt,
                                                 const float* __restrict__ bias,
                                                 unsigned short* __restrict__ outp) {
    const int LD = 56;
    __shared__ __align__(16) unsigned short As[128 * LD];
    __shared__ __align__(16) unsigned short Bs[128 * LD];
    int t = threadIdx.x;
    int wave = t >> 6, lane = t & 63;
    int wm = (wave >> 1) * 64, wn = (wave & 1) * 64;
    int m0 = blockIdx.y * 128, n0 = blockIdx.x * 128;
    int mrow = lane & 15, kq = (lane >> 4) * 8;
    v4f acc[4][4] = {};
    int lr = t >> 1;
    int lc0 = (t & 1) * 16;
    for (int k0 = 0; k0 < 512; k0 += 32) {
        v8s a0 = *(const v8s*)&A[(size_t)(m0 + lr) * 512 + k0 + lc0];
        v8s a1 = *(const v8s*)&A[(size_t)(m0 + lr) * 512 + k0 + lc0 + 8];
        v8s b0 = *(const v8s*)&Bt[(size_t)(n0 + lr) * 512 + k0 + lc0];
        v8s b1 = *(const v8s*)&Bt[(size_t)(n0 + lr) * 512 + k0 + lc0 + 8];
        __syncthreads();
        *(v8s*)&As[lr * LD + lc0] = a0;
        *(v8s*)&As[lr * LD + lc0 + 8] = a1;
        *(v8s*)&Bs[lr * LD + lc0] = b0;
        *(v8s*)&Bs[lr * LD + lc0 + 8] = b1;
        __syncthreads();
        v8s af[4], bf[4];
#pragma unroll
        for (int i = 0; i < 4; i++) af[i] = *(v8s*)&As[(wm + i * 16 + mrow) * LD + kq];
#pragma unroll
        for (int i = 0; i < 4; i++) bf[i] = *(v8s*)&Bs[(wn + i * 16 + mrow) * LD + kq];
#pragma unroll
        for (int i = 0; i < 4; i++)
#pragma unroll
            for (int j = 0; j < 4; j++)
                acc[i][j] = __builtin_amdgcn_mfma_f32_16x16x32_bf16(af[i], bf[j], acc[i][j], 0, 0, 0);
    }
#pragma unroll
    for (int j = 0; j < 4; j++) {
        int col = n0 + wn + j * 16 + mrow;
        float bv = bias[col];
#pragma unroll
        for (int i = 0; i < 4; i++) {
            int row = m0 + wm + i * 16 + (lane >> 4) * 4;
#pragma unroll
            for (int r = 0; r < 4; r++)
                outp[(size_t)(row + r) * 512 + col] = f2b(acc[i][j][r] + bv);
        }
    }
}

// ---------------- kv = k^T v per (b,h) + ksum; 8 N-chunks, fp32 atomics -------------
__global__ __launch_bounds__(256) void kv_kernel(const unsigned short* __restrict__ kbuf,
                                                 const unsigned short* __restrict__ vbuf,
                                                 float* __restrict__ kv,
                                                 float* __restrict__ ksum) {
    int bh = blockIdx.x;  // 0..63
    int b = bh >> 3, h = bh & 7;
    int nc = blockIdx.y;  // 0..7
    __shared__ __align__(16) unsigned short kb[64 * 64];
    __shared__ __align__(16) unsigned short vb[64 * 64];
    int t = threadIdx.x;
    int dk = t >> 2, dvb = (t & 3) * 16;
    float acc[16] = {};
    float ks = 0.0f;
    int lr = t >> 2, lc = (t & 3) * 16;
    for (int n0 = nc * 512; n0 < nc * 512 + 512; n0 += 64) {
        __syncthreads();
        size_t base = ((size_t)(b * 4096 + n0 + lr)) * 512 + h * 64;
        *(v8s*)&kb[lr * 64 + lc]     = *(const v8s*)&kbuf[base + lc];
        *(v8s*)&kb[lr * 64 + lc + 8] = *(const v8s*)&kbuf[base + lc + 8];
        *(v8s*)&vb[lr * 64 + lc]     = *(const v8s*)&vbuf[base + lc];
        *(v8s*)&vb[lr * 64 + lc + 8] = *(const v8s*)&vbuf[base + lc + 8];
        __syncthreads();
        for (int nn = 0; nn < 64; nn++) {
            float kvl = b2f(kb[nn * 64 + dk]);
            ks += kvl;
#pragma unroll
            for (int i = 0; i < 16; i++) acc[i] += kvl * b2f(vb[nn * 64 + dvb + i]);
        }
    }
    float* dst = kv + ((size_t)bh * 64 + dk) * 64 + dvb;
#pragma unroll
    for (int i = 0; i < 16; i++) atomicAdd(&dst[i], acc[i]);
    if ((t & 3) == 0) atomicAdd(&ksum[bh * 64 + dk], ks);
}

// ---------------- attn = (q @ kv) / max(q . max(ksum,100), 100); IN-PLACE over q ----------------
__global__ __launch_bounds__(256) void attn_kernel(unsigned short* qa,
                                                   const float* __restrict__ kv,
                                                   const float* __restrict__ ksum) {
    int bh = blockIdx.y;
    int b = bh >> 3, h = bh & 7;
    int nt = blockIdx.x;
    __shared__ float kvs[64 * 64];
    __shared__ float nrm[64];
    int t = threadIdx.x;
    for (int i = t; i < 4096; i += 256) kvs[i] = kv[(size_t)bh * 4096 + i];
    if (t < 64) nrm[t] = fmaxf(ksum[bh * 64 + t], 100.0f);
    __syncthreads();
    int n = nt * 256 + t;
    unsigned short* qp = qa + ((size_t)(b * 4096 + n)) * 512 + h * 64;
    float qf[64];
#pragma unroll
    for (int i = 0; i < 64; i += 8) {
        v8s v = *(const v8s*)&qp[i];
#pragma unroll
        for (int j = 0; j < 8; j++) qf[i + j] = b2f((unsigned short)v[j]);
    }
    float denom = 0.0f;
#pragma unroll
    for (int d = 0; d < 64; d++) denom += qf[d] * nrm[d];
    denom = fmaxf(denom, 100.0f);
    float inv = 1.0f / denom;
#pragma unroll
    for (int dv = 0; dv < 64; dv += 16) {
        float o[16] = {};
        for (int dk = 0; dk < 64; dk++) {
            float q = qf[dk];
#pragma unroll
            for (int i = 0; i < 16; i++) o[i] += q * kvs[dk * 64 + dv + i];
        }
#pragma unroll
        for (int i = 0; i < 16; i++) qp[dv + i] = f2b(o[i] * inv);
    }
}

// ---------------- depthwise conv 7x7 + exact GELU + BN-stat atomics (block per (b,c)) -----------
__global__ __launch_bounds__(256) void dwconv7_gelu(const unsigned short* __restrict__ in,
                                                    const float* __restrict__ w,
                                                    const float* __restrict__ bias,
                                                    unsigned short* __restrict__ out,
                                                    float* __restrict__ bn_sum,
                                                    float* __restrict__ bn_sumsq) {
    int bc = blockIdx.x;
    int c = bc & 511;
    __shared__ unsigned short img[70 * 72];
    __shared__ float wt[49];
    __shared__ float r1[4], r2[4];
    int t = threadIdx.x;
    for (int i = t; i < 70 * 72; i += 256) img[i] = 0;
    if (t < 49) wt[t] = w[c * 49 + t];
    __syncthreads();
    const unsigned short* src = in + (size_t)bc * 4096;
    for (int p = t; p < 4096; p += 256) {
        int hh = p >> 6, ww = p & 63;
        img[(hh + 3) * 72 + ww + 3] = src[p];
    }
    __syncthreads();
    float bv = bias[c];
    float s = 0.0f, s2 = 0.0f;
    unsigned short* dst = out + (size_t)bc * 4096;
    for (int p = t; p < 4096; p += 256) {
        int hh = p >> 6, ww = p & 63;
        float acc = bv;
#pragma unroll
        for (int kh = 0; kh < 7; kh++)
#pragma unroll
            for (int kw = 0; kw < 7; kw++)
                acc += b2f(img[(hh + kh) * 72 + ww + kw]) * wt[kh * 7 + kw];
        float ge = 0.5f * acc * (1.0f + erff(acc * 0.70710678118f));
        dst[p] = f2b(ge);
        s += ge;
        s2 += ge * ge;
    }
    for (int o = 32; o > 0; o >>= 1) {
        s += __shfl_down(s, o);
        s2 += __shfl_down(s2, o);
    }
    int wave = t >> 6, lane = t & 63;
    if (lane == 0) { r1[wave] = s; r2[wave] = s2; }
    __syncthreads();
    if (t == 0) {
        atomicAdd(&bn_sum[c], r1[0] + r1[1] + r1[2] + r1[3]);
        atomicAdd(&bn_sumsq[c], r2[0] + r2[1] + r2[2] + r2[3]);
    }
}

__global__ void bn_finalize(const float* __restrict__ s, const float* __restrict__ s2,
                            const float* __restrict__ g, const float* __restrict__ b,
                            float2* __restrict__ ab) {
    int c = blockIdx.x * blockDim.x + threadIdx.x;
    if (c >= 512) return;
    float m = s[c] * (1.0f / 32768.0f);
    float var = s2[c] * (1.0f / 32768.0f) - m * m;
    float inv = rsqrtf(var + 1e-5f);
    float sc = g[c] * inv;
    ab[c] = make_float2(sc, b[c] - m * sc);
}

// ---------------- depthwise conv 7x7 with BN affine applied on LDS load -------------------------
__global__ __launch_bounds__(256) void dwconv7_bn(const unsigned short* __restrict__ in,
                                                  const float2* __restrict__ bnab,
                                                  const float* __restrict__ w,
                                                  const float* __restrict__ bias,
                                                  unsigned short* __restrict__ out) {
    int bc = blockIdx.x;
    int c = bc & 511;
    __shared__ float img[70 * 72];
    __shared__ float wt[49];
    int t = threadIdx.x;
    for (int i = t; i < 70 * 72; i += 256) img[i] = 0.0f;
    if (t < 49) wt[t] = w[c * 49 + t];
    __syncthreads();
    float2 ab = bnab[c];
    const unsigned short* src = in + (size_t)bc * 4096;
    for (int p = t; p < 4096; p += 256) {
        int hh = p >> 6, ww = p & 63;
        img[(hh + 3) * 72 + ww + 3] = b2f(src[p]) * ab.x + ab.y;
    }
    __syncthreads();
    float bv = bias[c];
    unsigned short* dst = out + (size_t)bc * 4096;
    for (int p = t; p < 4096; p += 256) {
        int hh = p >> 6, ww = p & 63;
        float acc = bv;
#pragma unroll
        for (int kh = 0; kh < 7; kh++)
#pragma unroll
            for (int kw = 0; kw < 7; kw++)
                acc += img[(hh + kh) * 72 + ww + kw] * wt[kh * 7 + kw];
        dst[p] = f2b(acc);
    }
}

// ---------------- final: out[b][n][c] = x(f32) + attn(bf16) + y2[b][c][n](bf16) -> f32 ----------
__global__ __launch_bounds__(256) void final_add(const float* __restrict__ x,
                                                 const unsigned short* __restrict__ attn,
                                                 const unsigned short* __restrict__ y2,
                                                 float* __restrict__ out) {
    __shared__ unsigned short tile[32][33];
    int b = blockIdx.z;
    int c0 = blockIdx.x * 32, n0 = blockIdx.y * 32;
    int tx = threadIdx.x, ty = threadIdx.y;
    for (int j = 0; j < 32; j += 8)
        tile[ty + j][tx] = y2[((size_t)(b * 512 + c0 + ty + j)) * 4096 + n0 + tx];
    __syncthreads();
    for (int j = 0; j < 32; j += 8) {
        int n = n0 + ty + j, cc = c0 + tx;
        size_t idx = ((size_t)(b * 4096 + n)) * 512 + cc;
        out[idx] = x[idx] + b2f(attn[idx]) + b2f(tile[tx][ty + j]);
    }
}

// ------------------------------------------------------------------------------------------------
extern "C" void kernel_launch(void* const* d_in, const int* in_sizes, int n_in,
                              void* d_out, int out_size, void* d_ws, size_t ws_size,
                              hipStream_t stream) {
    const float* x     = (const float*)d_in[0];
    const float* qkv_w = (const float*)d_in[1];
    const float* qkv_b = (const float*)d_in[2];
    const float* out_w = (const float*)d_in[3];
    const float* out_b = (const float*)d_in[4];
    const float* pre_g = (const float*)d_in[5];
    const float* pre_b = (const float*)d_in[6];
    const float* lcm_g = (const float*)d_in[7];
    const float* lcm_b = (const float*)d_in[8];
    const float* ci_w  = (const float*)d_in[9];
    const float* ci_b  = (const float*)d_in[10];
    const float* bn_g  = (const float*)d_in[11];
    const float* bn_b  = (const float*)d_in[12];
    const float* co_w  = (const float*)d_in[13];
    const float* co_b  = (const float*)d_in[14];

    char* ws = (char*)d_ws;
    const size_t SLOT = 33554432;  // 32768*512*2 bytes (bf16)
    unsigned short* S0 = (unsigned short*)(ws);               // q -> attn -> xi -> y2
    unsigned short* S1 = (unsigned short*)(ws + SLOT);        // k -> attn_out(bf16)
    unsigned short* S2 = (unsigned short*)(ws + 2 * SLOT);    // v -> t -> y
    const size_t MISC = 3 * SLOT;                             // 96MB
    unsigned short* wT1 = (unsigned short*)(ws + MISC);                 // 1.5MB bf16
    unsigned short* wT2 = (unsigned short*)(ws + MISC + 1572864);       // 0.5MB bf16
    float* zbase        = (float*)(ws + MISC + 2097152);
    float* kvb          = zbase;                                        // 1MB
    float* ksum         = (float*)(ws + MISC + 2097152 + 1048576);      // 16KB
    float* bn_sum       = (float*)(ws + MISC + 2097152 + 1048576 + 16384);        // 2KB
    float* bn_sumsq     = (float*)(ws + MISC + 2097152 + 1048576 + 16384 + 2048); // 2KB
    float2* bnab        = (float2*)(ws + MISC + 3166208);              // 4KB
    float2* mstats      = (float2*)(ws + MISC + 3170304);              // 256KB
    float* outp         = (float*)d_out;

    dim3 tb(32, 8);
    // weight transpose + f32->bf16: qkv_w [512][1536] -> [1536][512]; out_w [512][512] -> T
    transpose_f2b<<<dim3(48, 16), tb, 0, stream>>>(qkv_w, wT1, 512, 1536);
    transpose_f2b<<<dim3(16, 16), tb, 0, stream>>>(out_w, wT2, 512, 512);
    ln_stats_kernel<<<32768, 256, 0, stream>>>(x, mstats);
    zero_fill<<<1044, 256, 0, stream>>>(zbase, 267264);  // kv+ksum+bn_sum+bn_sumsq
    // GEMM1 (LN fused): q->S0, k->S1, v->S2; relu on q,k
    gemm_ln_qkv<<<dim3(12, 256), 256, 0, stream>>>(x, mstats, pre_g, pre_b, wT1, qkv_b, S0, S1, S2);
    kv_kernel<<<dim3(64, 8), 256, 0, stream>>>(S1, S2, kvb, ksum);
    attn_kernel<<<dim3(16, 64), 256, 0, stream>>>(S0, kvb, ksum);  // in-place q->attn
    // GEMM2: attn_out(bf16) -> S1
    gemm_bf16<<<dim3(4, 256), 256, 0, stream>>>(S0, wT2, out_b, S1);
    // LN2 -> S2
    ln_bf16_kernel<<<32768, 256, 0, stream>>>(S1, lcm_g, lcm_b, S2);
    // transpose [B][4096][512] -> [B][512][4096] into S0
    transpose_bf16<<<dim3(16, 128, 8), tb, 0, stream>>>(S2, S0, 4096, 512);
    // conv1 + gelu + bn stats -> S2
    dwconv7_gelu<<<4096, 256, 0, stream>>>(S0, ci_w, ci_b, S2, bn_sum, bn_sumsq);
    bn_finalize<<<2, 256, 0, stream>>>(bn_sum, bn_sumsq, bn_g, bn_b, bnab);
    // conv2 (BN affine on load) -> S0
    dwconv7_bn<<<4096, 256, 0, stream>>>(S2, bnab, co_w, co_b, S0);
    // out = x + attn_out(S1) + transpose(y2 S0)
    final_add<<<dim3(16, 128, 8), tb, 0, stream>>>(x, S1, S0, outp);
}

// Round 4
// 716.293 us; speedup vs baseline: 1.2566x; 1.2566x over previous
//
#include <hip/hip_runtime.h>
#include <math.h>

typedef short v8s __attribute__((ext_vector_type(8)));
typedef float v4f __attribute__((ext_vector_type(4)));

__device__ __forceinline__ float b2f(unsigned short u) {
    return __uint_as_float(((unsigned)u) << 16);
}
__device__ __forceinline__ unsigned short f2b(float f) {
    unsigned u = __float_as_uint(f);
    unsigned r = (u + 0x7FFF + ((u >> 16) & 1)) >> 16;
    return (unsigned short)r;
}

// ---------------- zero fill ----------------
__global__ __launch_bounds__(256) void zero_fill(float* __restrict__ p, int n) {
    int i = blockIdx.x * 256 + threadIdx.x;
    if (i < n) p[i] = 0.0f;
}

// ---------------- LN row stats from fp32 x ----------------
__global__ __launch_bounds__(256) void ln_stats_kernel(const float* __restrict__ x,
                                                       float2* __restrict__ st) {
    size_t row = blockIdx.x;
    const float2* p = (const float2*)(x + row * 512);
    int t = threadIdx.x;
    float2 v = p[t];
    float s = v.x + v.y, s2 = v.x * v.x + v.y * v.y;
    for (int o = 32; o > 0; o >>= 1) {
        s += __shfl_down(s, o);
        s2 += __shfl_down(s2, o);
    }
    __shared__ float rs[4], rq[4];
    int wave = t >> 6, lane = t & 63;
    if (lane == 0) { rs[wave] = s; rq[wave] = s2; }
    __syncthreads();
    if (t == 0) {
        float ts = rs[0] + rs[1] + rs[2] + rs[3];
        float tq = rq[0] + rq[1] + rq[2] + rq[3];
        float mean = ts * (1.0f / 512.0f);
        float var = tq * (1.0f / 512.0f) - mean * mean;
        st[row] = make_float2(mean, rsqrtf(var + 1e-5f));
    }
}

// ---------------- LayerNorm: bf16 in -> bf16 out, fp32 gamma/beta (LN2) ----------------
__global__ __launch_bounds__(256) void ln_bf16_kernel(const unsigned short* __restrict__ in,
                                                      const float* __restrict__ g,
                                                      const float* __restrict__ bt,
                                                      unsigned short* __restrict__ out) {
    size_t row = blockIdx.x;
    const unsigned short* p = in + row * 512;
    int t = threadIdx.x;
    float v0 = b2f(p[t]);
    float v1 = b2f(p[t + 256]);
    float s = v0 + v1, s2 = v0 * v0 + v1 * v1;
    for (int o = 32; o > 0; o >>= 1) {
        s += __shfl_down(s, o);
        s2 += __shfl_down(s2, o);
    }
    __shared__ float rs[4], rq[4];
    int wave = t >> 6, lane = t & 63;
    if (lane == 0) { rs[wave] = s; rq[wave] = s2; }
    __syncthreads();
    float ts = rs[0] + rs[1] + rs[2] + rs[3];
    float tq = rq[0] + rq[1] + rq[2] + rq[3];
    float mean = ts * (1.0f / 512.0f);
    float var = tq * (1.0f / 512.0f) - mean * mean;
    float inv = rsqrtf(var + 1e-5f);
    unsigned short* o0 = out + row * 512;
    o0[t]       = f2b((v0 - mean) * inv * g[t]       + bt[t]);
    o0[t + 256] = f2b((v1 - mean) * inv * g[t + 256] + bt[t + 256]);
}

// ---------------- weight transpose + fp32->bf16 ----------------
__global__ __launch_bounds__(256) void transpose_f2b(const float* __restrict__ in,
                                                     unsigned short* __restrict__ out,
                                                     int R, int C) {
    __shared__ unsigned short tile[32][33];
    int c0 = blockIdx.x * 32, r0 = blockIdx.y * 32;
    int tx = threadIdx.x, ty = threadIdx.y;
    for (int j = 0; j < 32; j += 8)
        tile[ty + j][tx] = f2b(in[(size_t)(r0 + ty + j) * C + c0 + tx]);
    __syncthreads();
    for (int j = 0; j < 32; j += 8)
        out[(size_t)(c0 + ty + j) * R + r0 + tx] = tile[tx][ty + j];
}

// ---------------- tiled bf16 transpose ----------------
__global__ __launch_bounds__(256) void transpose_bf16(const unsigned short* __restrict__ in,
                                                      unsigned short* __restrict__ out,
                                                      int R, int C) {
    __shared__ unsigned short tile[32][33];
    size_t boff = (size_t)blockIdx.z * R * C;
    int c0 = blockIdx.x * 32, r0 = blockIdx.y * 32;
    int tx = threadIdx.x, ty = threadIdx.y;
    for (int j = 0; j < 32; j += 8)
        tile[ty + j][tx] = in[boff + (size_t)(r0 + ty + j) * C + c0 + tx];
    __syncthreads();
    for (int j = 0; j < 32; j += 8)
        out[boff + (size_t)(c0 + ty + j) * R + r0 + tx] = tile[tx][ty + j];
}

// ---------------- GEMM1, LN fused into A staging; q/k/v slot outputs, relu on q,k ---------------
__global__ __launch_bounds__(256) void gemm_ln_qkv(const float* __restrict__ x,
                                                   const float2* __restrict__ st,
                                                   const float* __restrict__ g,
                                                   const float* __restrict__ bvec,
                                                   const unsigned short* __restrict__ Bt,
                                                   const float* __restrict__ bias,
                                                   unsigned short* __restrict__ oq,
                                                   unsigned short* __restrict__ ok,
                                                   unsigned short* __restrict__ ov) {
    const int LD = 56;
    __shared__ __align__(16) unsigned short As[128 * LD];
    __shared__ __align__(16) unsigned short Bs[128 * LD];
    int t = threadIdx.x;
    int wave = t >> 6, lane = t & 63;
    int wm = (wave >> 1) * 64, wn = (wave & 1) * 64;
    int m0 = blockIdx.y * 128, n0 = blockIdx.x * 128;
    int mrow = lane & 15, kq = (lane >> 4) * 8;
    v4f acc[4][4] = {};
    int lr = t >> 1;
    int lc0 = (t & 1) * 16;
    float2 mi = st[m0 + lr];
    for (int k0 = 0; k0 < 512; k0 += 32) {
        float xv[16], gv[16], bv[16];
        *(float4*)&xv[0]  = *(const float4*)&x[(size_t)(m0 + lr) * 512 + k0 + lc0];
        *(float4*)&xv[4]  = *(const float4*)&x[(size_t)(m0 + lr) * 512 + k0 + lc0 + 4];
        *(float4*)&xv[8]  = *(const float4*)&x[(size_t)(m0 + lr) * 512 + k0 + lc0 + 8];
        *(float4*)&xv[12] = *(const float4*)&x[(size_t)(m0 + lr) * 512 + k0 + lc0 + 12];
        *(float4*)&gv[0]  = *(const float4*)&g[k0 + lc0];
        *(float4*)&gv[4]  = *(const float4*)&g[k0 + lc0 + 4];
        *(float4*)&gv[8]  = *(const float4*)&g[k0 + lc0 + 8];
        *(float4*)&gv[12] = *(const float4*)&g[k0 + lc0 + 12];
        *(float4*)&bv[0]  = *(const float4*)&bvec[k0 + lc0];
        *(float4*)&bv[4]  = *(const float4*)&bvec[k0 + lc0 + 4];
        *(float4*)&bv[8]  = *(const float4*)&bvec[k0 + lc0 + 8];
        *(float4*)&bv[12] = *(const float4*)&bvec[k0 + lc0 + 12];
        v8s wv0 = *(const v8s*)&Bt[(size_t)(n0 + lr) * 512 + k0 + lc0];
        v8s wv1 = *(const v8s*)&Bt[(size_t)(n0 + lr) * 512 + k0 + lc0 + 8];
        v8s na0, na1;
#pragma unroll
        for (int j = 0; j < 8; j++) {
            na0[j] = (short)f2b((xv[j]     - mi.x) * mi.y * gv[j]     + bv[j]);
            na1[j] = (short)f2b((xv[j + 8] - mi.x) * mi.y * gv[j + 8] + bv[j + 8]);
        }
        __syncthreads();
        *(v8s*)&As[lr * LD + lc0] = na0;
        *(v8s*)&As[lr * LD + lc0 + 8] = na1;
        *(v8s*)&Bs[lr * LD + lc0] = wv0;
        *(v8s*)&Bs[lr * LD + lc0 + 8] = wv1;
        __syncthreads();
        v8s af[4], bf[4];
#pragma unroll
        for (int i = 0; i < 4; i++) af[i] = *(v8s*)&As[(wm + i * 16 + mrow) * LD + kq];
#pragma unroll
        for (int i = 0; i < 4; i++) bf[i] = *(v8s*)&Bs[(wn + i * 16 + mrow) * LD + kq];
#pragma unroll
        for (int i = 0; i < 4; i++)
#pragma unroll
            for (int j = 0; j < 4; j++)
                acc[i][j] = __builtin_amdgcn_mfma_f32_16x16x32_bf16(af[i], bf[j], acc[i][j], 0, 0, 0);
    }
#pragma unroll
    for (int j = 0; j < 4; j++) {
        int col = n0 + wn + j * 16 + mrow;
        float bv = bias[col];
        int seg = col >> 9;
        int c = col & 511;
        unsigned short* base = (seg == 0) ? oq : ((seg == 1) ? ok : ov);
        bool doRelu = col < 1024;
#pragma unroll
        for (int i = 0; i < 4; i++) {
            int row = m0 + wm + i * 16 + (lane >> 4) * 4;
#pragma unroll
            for (int r = 0; r < 4; r++) {
                float v = acc[i][j][r] + bv;
                if (doRelu) v = fmaxf(v, 0.0f);
                base[(size_t)(row + r) * 512 + c] = f2b(v);
            }
        }
    }
}

// ---------------- GEMM2: bf16 A * Bt + fp32 bias -> bf16 out ----------------
__global__ __launch_bounds__(256) void gemm_bf16(const unsigned short* __restrict__ A,
                                                 const unsigned short* __restrict__ Bt,
                                                 const float* __restrict__ bias,
                                                 unsigned short* __restrict__ outp) {
    const int LD = 56;
    __shared__ __align__(16) unsigned short As[128 * LD];
    __shared__ __align__(16) unsigned short Bs[128 * LD];
    int t = threadIdx.x;
    int wave = t >> 6, lane = t & 63;
    int wm = (wave >> 1) * 64, wn = (wave & 1) * 64;
    int m0 = blockIdx.y * 128, n0 = blockIdx.x * 128;
    int mrow = lane & 15, kq = (lane >> 4) * 8;
    v4f acc[4][4] = {};
    int lr = t >> 1;
    int lc0 = (t & 1) * 16;
    for (int k0 = 0; k0 < 512; k0 += 32) {
        v8s a0 = *(const v8s*)&A[(size_t)(m0 + lr) * 512 + k0 + lc0];
        v8s a1 = *(const v8s*)&A[(size_t)(m0 + lr) * 512 + k0 + lc0 + 8];
        v8s b0 = *(const v8s*)&Bt[(size_t)(n0 + lr) * 512 + k0 + lc0];
        v8s b1 = *(const v8s*)&Bt[(size_t)(n0 + lr) * 512 + k0 + lc0 + 8];
        __syncthreads();
        *(v8s*)&As[lr * LD + lc0] = a0;
        *(v8s*)&As[lr * LD + lc0 + 8] = a1;
        *(v8s*)&Bs[lr * LD + lc0] = b0;
        *(v8s*)&Bs[lr * LD + lc0 + 8] = b1;
        __syncthreads();
        v8s af[4], bf[4];
#pragma unroll
        for (int i = 0; i < 4; i++) af[i] = *(v8s*)&As[(wm + i * 16 + mrow) * LD + kq];
#pragma unroll
        for (int i = 0; i < 4; i++) bf[i] = *(v8s*)&Bs[(wn + i * 16 + mrow) * LD + kq];
#pragma unroll
        for (int i = 0; i < 4; i++)
#pragma unroll
            for (int j = 0; j < 4; j++)
                acc[i][j] = __builtin_amdgcn_mfma_f32_16x16x32_bf16(af[i], bf[j], acc[i][j], 0, 0, 0);
    }
#pragma unroll
    for (int j = 0; j < 4; j++) {
        int col = n0 + wn + j * 16 + mrow;
        float bv = bias[col];
#pragma unroll
        for (int i = 0; i < 4; i++) {
            int row = m0 + wm + i * 16 + (lane >> 4) * 4;
#pragma unroll
            for (int r = 0; r < 4; r++)
                outp[(size_t)(row + r) * 512 + col] = f2b(acc[i][j][r] + bv);
        }
    }
}

// ---------------- kv = k^T v per (b,h) + ksum ----------------
__global__ __launch_bounds__(256) void kv_kernel(const unsigned short* __restrict__ kbuf,
                                                 const unsigned short* __restrict__ vbuf,
                                                 float* __restrict__ kv,
                                                 float* __restrict__ ksum) {
    int bh = blockIdx.x;
    int b = bh >> 3, h = bh & 7;
    int nc = blockIdx.y;
    __shared__ __align__(16) unsigned short kb[64 * 64];
    __shared__ __align__(16) unsigned short vb[64 * 64];
    int t = threadIdx.x;
    int dk = t >> 2, dvb = (t & 3) * 16;
    float acc[16] = {};
    float ks = 0.0f;
    int lr = t >> 2, lc = (t & 3) * 16;
    for (int n0 = nc * 512; n0 < nc * 512 + 512; n0 += 64) {
        __syncthreads();
        size_t base = ((size_t)(b * 4096 + n0 + lr)) * 512 + h * 64;
        *(v8s*)&kb[lr * 64 + lc]     = *(const v8s*)&kbuf[base + lc];
        *(v8s*)&kb[lr * 64 + lc + 8] = *(const v8s*)&kbuf[base + lc + 8];
        *(v8s*)&vb[lr * 64 + lc]     = *(const v8s*)&vbuf[base + lc];
        *(v8s*)&vb[lr * 64 + lc + 8] = *(const v8s*)&vbuf[base + lc + 8];
        __syncthreads();
        for (int nn = 0; nn < 64; nn++) {
            float kvl = b2f(kb[nn * 64 + dk]);
            ks += kvl;
#pragma unroll
            for (int i = 0; i < 16; i++) acc[i] += kvl * b2f(vb[nn * 64 + dvb + i]);
        }
    }
    float* dst = kv + ((size_t)bh * 64 + dk) * 64 + dvb;
#pragma unroll
    for (int i = 0; i < 16; i++) atomicAdd(&dst[i], acc[i]);
    if ((t & 3) == 0) atomicAdd(&ksum[bh * 64 + dk], ks);
}

// ---------------- attn; IN-PLACE over q ----------------
__global__ __launch_bounds__(256) void attn_kernel(unsigned short* qa,
                                                   const float* __restrict__ kv,
                                                   const float* __restrict__ ksum) {
    int bh = blockIdx.y;
    int b = bh >> 3, h = bh & 7;
    int nt = blockIdx.x;
    __shared__ float kvs[64 * 64];
    __shared__ float nrm[64];
    int t = threadIdx.x;
    for (int i = t; i < 4096; i += 256) kvs[i] = kv[(size_t)bh * 4096 + i];
    if (t < 64) nrm[t] = fmaxf(ksum[bh * 64 + t], 100.0f);
    __syncthreads();
    int n = nt * 256 + t;
    unsigned short* qp = qa + ((size_t)(b * 4096 + n)) * 512 + h * 64;
    float qf[64];
#pragma unroll
    for (int i = 0; i < 64; i += 8) {
        v8s v = *(const v8s*)&qp[i];
#pragma unroll
        for (int j = 0; j < 8; j++) qf[i + j] = b2f((unsigned short)v[j]);
    }
    float denom = 0.0f;
#pragma unroll
    for (int d = 0; d < 64; d++) denom += qf[d] * nrm[d];
    denom = fmaxf(denom, 100.0f);
    float inv = 1.0f / denom;
#pragma unroll
    for (int dv = 0; dv < 64; dv += 16) {
        float o[16] = {};
        for (int dk = 0; dk < 64; dk++) {
            float q = qf[dk];
#pragma unroll
            for (int i = 0; i < 16; i++) o[i] += q * kvs[dk * 64 + dv + i];
        }
#pragma unroll
        for (int i = 0; i < 16; i++) qp[dv + i] = f2b(o[i] * inv);
    }
}

// ---------------- depthwise conv 7x7 + GELU + BN stats; column-sliding, 16 rows/thread ----------
// block = 256 threads: tx = w (0..63), ty = h-group (0..3), each thread 16 output rows
__global__ __launch_bounds__(256) void dwconv7_gelu(const unsigned short* __restrict__ in,
                                                    const float* __restrict__ w,
                                                    const float* __restrict__ bias,
                                                    unsigned short* __restrict__ out,
                                                    float* __restrict__ bn_sum,
                                                    float* __restrict__ bn_sumsq) {
    int bc = blockIdx.x;
    int c = bc & 511;
    __shared__ float img[70 * 72];
    __shared__ float wsm[49];
    __shared__ float r1[4], r2[4];
    int t = threadIdx.x;
    int tx = t & 63, ty = t >> 6;
    for (int i = t; i < 70 * 72; i += 256) img[i] = 0.0f;
    if (t < 49) wsm[t] = w[c * 49 + t];
    __syncthreads();
    const unsigned short* src = in + (size_t)bc * 4096;
    for (int p = t; p < 4096; p += 256)
        img[((p >> 6) + 3) * 72 + (p & 63) + 3] = b2f(src[p]);
    __syncthreads();
    float wt[49];
#pragma unroll
    for (int i = 0; i < 49; i++) wt[i] = wsm[i];
    float bv = bias[c];
    float acc[16];
#pragma unroll
    for (int i = 0; i < 16; i++) acc[i] = bv;
    int h0 = ty * 16;
#pragma unroll
    for (int rr = 0; rr < 22; rr++) {
        float v[7];
#pragma unroll
        for (int kw = 0; kw < 7; kw++) v[kw] = img[(h0 + rr) * 72 + tx + kw];
#pragma unroll
        for (int kh = 0; kh < 7; kh++) {
            int o = rr - kh;
            if (o >= 0 && o <= 15) {
                float dot = v[0] * wt[kh * 7];
#pragma unroll
                for (int kw = 1; kw < 7; kw++) dot += v[kw] * wt[kh * 7 + kw];
                acc[o] += dot;
            }
        }
    }
    float s = 0.0f, s2 = 0.0f;
    unsigned short* dst = out + (size_t)bc * 4096;
#pragma unroll
    for (int i = 0; i < 16; i++) {
        float a = acc[i];
        float ge = 0.5f * a * (1.0f + erff(a * 0.70710678118f));
        dst[(h0 + i) * 64 + tx] = f2b(ge);
        s += ge;
        s2 += ge * ge;
    }
    for (int o = 32; o > 0; o >>= 1) {
        s += __shfl_down(s, o);
        s2 += __shfl_down(s2, o);
    }
    int lane = t & 63;
    if (lane == 0) { r1[ty] = s; r2[ty] = s2; }
    __syncthreads();
    if (t == 0) {
        atomicAdd(&bn_sum[c], r1[0] + r1[1] + r1[2] + r1[3]);
        atomicAdd(&bn_sumsq[c], r2[0] + r2[1] + r2[2] + r2[3]);
    }
}

__global__ void bn_finalize(const float* __restrict__ s, const float* __restrict__ s2,
                            const float* __restrict__ g, const float* __restrict__ b,
                            float2* __restrict__ ab) {
    int c = blockIdx.x * blockDim.x + threadIdx.x;
    if (c >= 512) return;
    float m = s[c] * (1.0f / 32768.0f);
    float var = s2[c] * (1.0f / 32768.0f) - m * m;
    float inv = rsqrtf(var + 1e-5f);
    float sc = g[c] * inv;
    ab[c] = make_float2(sc, b[c] - m * sc);
}

// ---------------- depthwise conv 7x7 with BN affine on load; column-sliding -------------------
__global__ __launch_bounds__(256) void dwconv7_bn(const unsigned short* __restrict__ in,
                                                  const float2* __restrict__ bnab,
                                                  const float* __restrict__ w,
                                                  const float* __restrict__ bias,
                                                  unsigned short* __restrict__ out) {
    int bc = blockIdx.x;
    int c = bc & 511;
    __shared__ float img[70 * 72];
    __shared__ float wsm[49];
    int t = threadIdx.x;
    int tx = t & 63, ty = t >> 6;
    for (int i = t; i < 70 * 72; i += 256) img[i] = 0.0f;
    if (t < 49) wsm[t] = w[c * 49 + t];
    __syncthreads();
    float2 ab = bnab[c];
    const unsigned short* src = in + (size_t)bc * 4096;
    for (int p = t; p < 4096; p += 256)
        img[((p >> 6) + 3) * 72 + (p & 63) + 3] = b2f(src[p]) * ab.x + ab.y;
    __syncthreads();
    float wt[49];
#pragma unroll
    for (int i = 0; i < 49; i++) wt[i] = wsm[i];
    float bv = bias[c];
    float acc[16];
#pragma unroll
    for (int i = 0; i < 16; i++) acc[i] = bv;
    int h0 = ty * 16;
#pragma unroll
    for (int rr = 0; rr < 22; rr++) {
        float v[7];
#pragma unroll
        for (int kw = 0; kw < 7; kw++) v[kw] = img[(h0 + rr) * 72 + tx + kw];
#pragma unroll
        for (int kh = 0; kh < 7; kh++) {
            int o = rr - kh;
            if (o >= 0 && o <= 15) {
                float dot = v[0] * wt[kh * 7];
#pragma unroll
                for (int kw = 1; kw < 7; kw++) dot += v[kw] * wt[kh * 7 + kw];
                acc[o] += dot;
            }
        }
    }
    unsigned short* dst = out + (size_t)bc * 4096;
#pragma unroll
    for (int i = 0; i < 16; i++)
        dst[(h0 + i) * 64 + tx] = f2b(acc[i]);
}

// ---------------- final: out = x(f32) + attn(bf16) + y2^T(bf16) -> f32 ----------------
__global__ __launch_bounds__(256) void final_add(const float* __restrict__ x,
                                                 const unsigned short* __restrict__ attn,
                                                 const unsigned short* __restrict__ y2,
                                                 float* __restrict__ out) {
    __shared__ unsigned short tile[32][33];
    int b = blockIdx.z;
    int c0 = blockIdx.x * 32, n0 = blockIdx.y * 32;
    int tx = threadIdx.x, ty = threadIdx.y;
    for (int j = 0; j < 32; j += 8)
        tile[ty + j][tx] = y2[((size_t)(b * 512 + c0 + ty + j)) * 4096 + n0 + tx];
    __syncthreads();
    for (int j = 0; j < 32; j += 8) {
        int n = n0 + ty + j, cc = c0 + tx;
        size_t idx = ((size_t)(b * 4096 + n)) * 512 + cc;
        out[idx] = x[idx] + b2f(attn[idx]) + b2f(tile[tx][ty + j]);
    }
}

// ------------------------------------------------------------------------------------------------
extern "C" void kernel_launch(void* const* d_in, const int* in_sizes, int n_in,
                              void* d_out, int out_size, void* d_ws, size_t ws_size,
                              hipStream_t stream) {
    const float* x     = (const float*)d_in[0];
    const float* qkv_w = (const float*)d_in[1];
    const float* qkv_b = (const float*)d_in[2];
    const float* out_w = (const float*)d_in[3];
    const float* out_b = (const float*)d_in[4];
    const float* pre_g = (const float*)d_in[5];
    const float* pre_b = (const float*)d_in[6];
    const float* lcm_g = (const float*)d_in[7];
    const float* lcm_b = (const float*)d_in[8];
    const float* ci_w  = (const float*)d_in[9];
    const float* ci_b  = (const float*)d_in[10];
    const float* bn_g  = (const float*)d_in[11];
    const float* bn_b  = (const float*)d_in[12];
    const float* co_w  = (const float*)d_in[13];
    const float* co_b  = (const float*)d_in[14];

    char* ws = (char*)d_ws;
    const size_t SLOT = 33554432;  // 32768*512*2 bytes (bf16)
    unsigned short* S0 = (unsigned short*)(ws);               // q -> attn -> xi -> y2
    unsigned short* S1 = (unsigned short*)(ws + SLOT);        // k -> attn_out(bf16)
    unsigned short* S2 = (unsigned short*)(ws + 2 * SLOT);    // v -> t -> y
    const size_t MISC = 3 * SLOT;                             // 96MB
    unsigned short* wT1 = (unsigned short*)(ws + MISC);                 // 1.5MB bf16
    unsigned short* wT2 = (unsigned short*)(ws + MISC + 1572864);       // 0.5MB bf16
    float* zbase        = (float*)(ws + MISC + 2097152);
    float* kvb          = zbase;                                        // 1MB
    float* ksum         = (float*)(ws + MISC + 2097152 + 1048576);      // 16KB
    float* bn_sum       = (float*)(ws + MISC + 2097152 + 1048576 + 16384);        // 2KB
    float* bn_sumsq     = (float*)(ws + MISC + 2097152 + 1048576 + 16384 + 2048); // 2KB
    float2* bnab        = (float2*)(ws + MISC + 3166208);              // 4KB
    float2* mstats      = (float2*)(ws + MISC + 3170304);              // 256KB
    float* outp         = (float*)d_out;

    dim3 tb(32, 8);
    transpose_f2b<<<dim3(48, 16), tb, 0, stream>>>(qkv_w, wT1, 512, 1536);
    transpose_f2b<<<dim3(16, 16), tb, 0, stream>>>(out_w, wT2, 512, 512);
    ln_stats_kernel<<<32768, 256, 0, stream>>>(x, mstats);
    zero_fill<<<1044, 256, 0, stream>>>(zbase, 267264);
    gemm_ln_qkv<<<dim3(12, 256), 256, 0, stream>>>(x, mstats, pre_g, pre_b, wT1, qkv_b, S0, S1, S2);
    kv_kernel<<<dim3(64, 8), 256, 0, stream>>>(S1, S2, kvb, ksum);
    attn_kernel<<<dim3(16, 64), 256, 0, stream>>>(S0, kvb, ksum);
    gemm_bf16<<<dim3(4, 256), 256, 0, stream>>>(S0, wT2, out_b, S1);
    ln_bf16_kernel<<<32768, 256, 0, stream>>>(S1, lcm_g, lcm_b, S2);
    transpose_bf16<<<dim3(16, 128, 8), tb, 0, stream>>>(S2, S0, 4096, 512);
    dwconv7_gelu<<<4096, 256, 0, stream>>>(S0, ci_w, ci_b, S2, bn_sum, bn_sumsq);
    bn_finalize<<<2, 256, 0, stream>>>(bn_sum, bn_sumsq, bn_g, bn_b, bnab);
    dwconv7_bn<<<4096, 256, 0, stream>>>(S2, bnab, co_w, co_b, S0);
    final_add<<<dim3(16, 128, 8), tb, 0, stream>>>(x, S1, S0, outp);
}

// Round 5
// 564.139 us; speedup vs baseline: 1.5955x; 1.2697x over previous
//
#include <hip/hip_runtime.h>
#include <math.h>

typedef short v8s __attribute__((ext_vector_type(8)));
typedef short v4s __attribute__((ext_vector_type(4)));
typedef float v4f __attribute__((ext_vector_type(4)));

__device__ __forceinline__ float b2f(unsigned short u) {
    return __uint_as_float(((unsigned)u) << 16);
}
__device__ __forceinline__ unsigned short f2b(float f) {
    unsigned u = __float_as_uint(f);
    unsigned r = (u + 0x7FFF + ((u >> 16) & 1)) >> 16;
    return (unsigned short)r;
}

// ---------------- zero fill ----------------
__global__ __launch_bounds__(256) void zero_fill(float* __restrict__ p, int n) {
    int i = blockIdx.x * 256 + threadIdx.x;
    if (i < n) p[i] = 0.0f;
}

// ---------------- LN1 fused: fp32 x -> bf16 normed ----------------
__global__ __launch_bounds__(256) void ln_apply(const float* __restrict__ x,
                                                const float* __restrict__ g,
                                                const float* __restrict__ bt,
                                                unsigned short* __restrict__ out) {
    size_t row = blockIdx.x;
    const float* p = x + row * 512;
    int t = threadIdx.x;
    float v0 = p[t];
    float v1 = p[t + 256];
    float s = v0 + v1, s2 = v0 * v0 + v1 * v1;
    for (int o = 32; o > 0; o >>= 1) {
        s += __shfl_down(s, o);
        s2 += __shfl_down(s2, o);
    }
    __shared__ float rs[4], rq[4];
    int wave = t >> 6, lane = t & 63;
    if (lane == 0) { rs[wave] = s; rq[wave] = s2; }
    __syncthreads();
    float ts = rs[0] + rs[1] + rs[2] + rs[3];
    float tq = rq[0] + rq[1] + rq[2] + rq[3];
    float mean = ts * (1.0f / 512.0f);
    float var = tq * (1.0f / 512.0f) - mean * mean;
    float inv = rsqrtf(var + 1e-5f);
    unsigned short* o0 = out + row * 512;
    o0[t]       = f2b((v0 - mean) * inv * g[t]       + bt[t]);
    o0[t + 256] = f2b((v1 - mean) * inv * g[t + 256] + bt[t + 256]);
}

// ---------------- LayerNorm: bf16 in -> bf16 out, fp32 gamma/beta (LN2) ----------------
__global__ __launch_bounds__(256) void ln_bf16_kernel(const unsigned short* __restrict__ in,
                                                      const float* __restrict__ g,
                                                      const float* __restrict__ bt,
                                                      unsigned short* __restrict__ out) {
    size_t row = blockIdx.x;
    const unsigned short* p = in + row * 512;
    int t = threadIdx.x;
    float v0 = b2f(p[t]);
    float v1 = b2f(p[t + 256]);
    float s = v0 + v1, s2 = v0 * v0 + v1 * v1;
    for (int o = 32; o > 0; o >>= 1) {
        s += __shfl_down(s, o);
        s2 += __shfl_down(s2, o);
    }
    __shared__ float rs[4], rq[4];
    int wave = t >> 6, lane = t & 63;
    if (lane == 0) { rs[wave] = s; rq[wave] = s2; }
    __syncthreads();
    float ts = rs[0] + rs[1] + rs[2] + rs[3];
    float tq = rq[0] + rq[1] + rq[2] + rq[3];
    float mean = ts * (1.0f / 512.0f);
    float var = tq * (1.0f / 512.0f) - mean * mean;
    float inv = rsqrtf(var + 1e-5f);
    unsigned short* o0 = out + row * 512;
    o0[t]       = f2b((v0 - mean) * inv * g[t]       + bt[t]);
    o0[t + 256] = f2b((v1 - mean) * inv * g[t + 256] + bt[t + 256]);
}

// ---------------- weight transpose + fp32->bf16 ----------------
__global__ __launch_bounds__(256) void transpose_f2b(const float* __restrict__ in,
                                                     unsigned short* __restrict__ out,
                                                     int R, int C) {
    __shared__ unsigned short tile[32][33];
    int c0 = blockIdx.x * 32, r0 = blockIdx.y * 32;
    int tx = threadIdx.x, ty = threadIdx.y;
    for (int j = 0; j < 32; j += 8)
        tile[ty + j][tx] = f2b(in[(size_t)(r0 + ty + j) * C + c0 + tx]);
    __syncthreads();
    for (int j = 0; j < 32; j += 8)
        out[(size_t)(c0 + ty + j) * R + r0 + tx] = tile[tx][ty + j];
}

// ---------------- tiled bf16 transpose ----------------
__global__ __launch_bounds__(256) void transpose_bf16(const unsigned short* __restrict__ in,
                                                      unsigned short* __restrict__ out,
                                                      int R, int C) {
    __shared__ unsigned short tile[32][33];
    size_t boff = (size_t)blockIdx.z * R * C;
    int c0 = blockIdx.x * 32, r0 = blockIdx.y * 32;
    int tx = threadIdx.x, ty = threadIdx.y;
    for (int j = 0; j < 32; j += 8)
        tile[ty + j][tx] = in[boff + (size_t)(r0 + ty + j) * C + c0 + tx];
    __syncthreads();
    for (int j = 0; j < 32; j += 8)
        out[boff + (size_t)(c0 + ty + j) * R + r0 + tx] = tile[tx][ty + j];
}

// ---------------- GEMM1: bf16 normed A * Bt -> q/k/v slots, relu on q,k ----------------
__global__ __launch_bounds__(256) void gemm_qkv(const unsigned short* __restrict__ A,
                                                const unsigned short* __restrict__ Bt,
                                                const float* __restrict__ bias,
                                                unsigned short* __restrict__ oq,
                                                unsigned short* __restrict__ ok,
                                                unsigned short* __restrict__ ov) {
    const int LD = 56;
    __shared__ __align__(16) unsigned short As[128 * LD];
    __shared__ __align__(16) unsigned short Bs[128 * LD];
    int t = threadIdx.x;
    int wave = t >> 6, lane = t & 63;
    int wm = (wave >> 1) * 64, wn = (wave & 1) * 64;
    int m0 = blockIdx.y * 128, n0 = blockIdx.x * 128;
    int mrow = lane & 15, kq = (lane >> 4) * 8;
    v4f acc[4][4] = {};
    int lr = t >> 1;
    int lc0 = (t & 1) * 16;
    for (int k0 = 0; k0 < 512; k0 += 32) {
        v8s a0 = *(const v8s*)&A[(size_t)(m0 + lr) * 512 + k0 + lc0];
        v8s a1 = *(const v8s*)&A[(size_t)(m0 + lr) * 512 + k0 + lc0 + 8];
        v8s b0 = *(const v8s*)&Bt[(size_t)(n0 + lr) * 512 + k0 + lc0];
        v8s b1 = *(const v8s*)&Bt[(size_t)(n0 + lr) * 512 + k0 + lc0 + 8];
        __syncthreads();
        *(v8s*)&As[lr * LD + lc0] = a0;
        *(v8s*)&As[lr * LD + lc0 + 8] = a1;
        *(v8s*)&Bs[lr * LD + lc0] = b0;
        *(v8s*)&Bs[lr * LD + lc0 + 8] = b1;
        __syncthreads();
        v8s af[4], bf[4];
#pragma unroll
        for (int i = 0; i < 4; i++) af[i] = *(v8s*)&As[(wm + i * 16 + mrow) * LD + kq];
#pragma unroll
        for (int i = 0; i < 4; i++) bf[i] = *(v8s*)&Bs[(wn + i * 16 + mrow) * LD + kq];
#pragma unroll
        for (int i = 0; i < 4; i++)
#pragma unroll
            for (int j = 0; j < 4; j++)
                acc[i][j] = __builtin_amdgcn_mfma_f32_16x16x32_bf16(af[i], bf[j], acc[i][j], 0, 0, 0);
    }
#pragma unroll
    for (int j = 0; j < 4; j++) {
        int col = n0 + wn + j * 16 + mrow;
        float bv = bias[col];
        int seg = col >> 9;
        int c = col & 511;
        unsigned short* base = (seg == 0) ? oq : ((seg == 1) ? ok : ov);
        bool doRelu = col < 1024;
#pragma unroll
        for (int i = 0; i < 4; i++) {
            int row = m0 + wm + i * 16 + (lane >> 4) * 4;
#pragma unroll
            for (int r = 0; r < 4; r++) {
                float v = acc[i][j][r] + bv;
                if (doRelu) v = fmaxf(v, 0.0f);
                base[(size_t)(row + r) * 512 + c] = f2b(v);
            }
        }
    }
}

// ---------------- GEMM2: bf16 A * Bt + fp32 bias -> bf16 out ----------------
__global__ __launch_bounds__(256) void gemm_bf16(const unsigned short* __restrict__ A,
                                                 const unsigned short* __restrict__ Bt,
                                                 const float* __restrict__ bias,
                                                 unsigned short* __restrict__ outp) {
    const int LD = 56;
    __shared__ __align__(16) unsigned short As[128 * LD];
    __shared__ __align__(16) unsigned short Bs[128 * LD];
    int t = threadIdx.x;
    int wave = t >> 6, lane = t & 63;
    int wm = (wave >> 1) * 64, wn = (wave & 1) * 64;
    int m0 = blockIdx.y * 128, n0 = blockIdx.x * 128;
    int mrow = lane & 15, kq = (lane >> 4) * 8;
    v4f acc[4][4] = {};
    int lr = t >> 1;
    int lc0 = (t & 1) * 16;
    for (int k0 = 0; k0 < 512; k0 += 32) {
        v8s a0 = *(const v8s*)&A[(size_t)(m0 + lr) * 512 + k0 + lc0];
        v8s a1 = *(const v8s*)&A[(size_t)(m0 + lr) * 512 + k0 + lc0 + 8];
        v8s b0 = *(const v8s*)&Bt[(size_t)(n0 + lr) * 512 + k0 + lc0];
        v8s b1 = *(const v8s*)&Bt[(size_t)(n0 + lr) * 512 + k0 + lc0 + 8];
        __syncthreads();
        *(v8s*)&As[lr * LD + lc0] = a0;
        *(v8s*)&As[lr * LD + lc0 + 8] = a1;
        *(v8s*)&Bs[lr * LD + lc0] = b0;
        *(v8s*)&Bs[lr * LD + lc0 + 8] = b1;
        __syncthreads();
        v8s af[4], bf[4];
#pragma unroll
        for (int i = 0; i < 4; i++) af[i] = *(v8s*)&As[(wm + i * 16 + mrow) * LD + kq];
#pragma unroll
        for (int i = 0; i < 4; i++) bf[i] = *(v8s*)&Bs[(wn + i * 16 + mrow) * LD + kq];
#pragma unroll
        for (int i = 0; i < 4; i++)
#pragma unroll
            for (int j = 0; j < 4; j++)
                acc[i][j] = __builtin_amdgcn_mfma_f32_16x16x32_bf16(af[i], bf[j], acc[i][j], 0, 0, 0);
    }
#pragma unroll
    for (int j = 0; j < 4; j++) {
        int col = n0 + wn + j * 16 + mrow;
        float bv = bias[col];
#pragma unroll
        for (int i = 0; i < 4; i++) {
            int row = m0 + wm + i * 16 + (lane >> 4) * 4;
#pragma unroll
            for (int r = 0; r < 4; r++)
                outp[(size_t)(row + r) * 512 + col] = f2b(acc[i][j][r] + bv);
        }
    }
}

// ---------------- kv partials: per (bh, chunk of 128 rows), no atomics ----------------
// thread tile: 4 dk x 4 dv; writes kvp[(bh*32+nc)*4096 + dk*64+dv], ksp[(bh*32+nc)*64+dk]
__global__ __launch_bounds__(256) void kv_part(const unsigned short* __restrict__ kbuf,
                                               const unsigned short* __restrict__ vbuf,
                                               float* __restrict__ kvp,
                                               float* __restrict__ ksp) {
    int bh = blockIdx.x;   // 0..63
    int b = bh >> 3, h = bh & 7;
    int nc = blockIdx.y;   // 0..31
    __shared__ __align__(16) unsigned short kb[64 * 64];
    __shared__ __align__(16) unsigned short vb[64 * 64];
    int t = threadIdx.x;
    int dk0 = (t >> 4) * 4;   // 0..60
    int dv0 = (t & 15) * 4;   // 0..60
    float acc[4][4] = {};
    float ks[4] = {};
    int lr = t >> 2, lc = (t & 3) * 16;
    for (int n0 = nc * 128; n0 < nc * 128 + 128; n0 += 64) {
        __syncthreads();
        size_t base = ((size_t)(b * 4096 + n0 + lr)) * 512 + h * 64;
        *(v8s*)&kb[lr * 64 + lc]     = *(const v8s*)&kbuf[base + lc];
        *(v8s*)&kb[lr * 64 + lc + 8] = *(const v8s*)&kbuf[base + lc + 8];
        *(v8s*)&vb[lr * 64 + lc]     = *(const v8s*)&vbuf[base + lc];
        *(v8s*)&vb[lr * 64 + lc + 8] = *(const v8s*)&vbuf[base + lc + 8];
        __syncthreads();
#pragma unroll 4
        for (int nn = 0; nn < 64; nn++) {
            v4s kr = *(const v4s*)&kb[nn * 64 + dk0];
            v4s vr = *(const v4s*)&vb[nn * 64 + dv0];
            float kf[4], vf[4];
#pragma unroll
            for (int i = 0; i < 4; i++) { kf[i] = b2f((unsigned short)kr[i]); vf[i] = b2f((unsigned short)vr[i]); }
#pragma unroll
            for (int i = 0; i < 4; i++) {
#pragma unroll
                for (int j = 0; j < 4; j++) acc[i][j] += kf[i] * vf[j];
            }
            if ((t & 15) == 0) {
#pragma unroll
                for (int i = 0; i < 4; i++) ks[i] += kf[i];
            }
        }
    }
    float* dst = kvp + ((size_t)(bh * 32 + nc)) * 4096;
#pragma unroll
    for (int i = 0; i < 4; i++)
        *(float4*)&dst[(dk0 + i) * 64 + dv0] = make_float4(acc[i][0], acc[i][1], acc[i][2], acc[i][3]);
    if ((t & 15) == 0) {
        float* kd = ksp + ((size_t)(bh * 32 + nc)) * 64;
#pragma unroll
        for (int i = 0; i < 4; i++) kd[dk0 + i] = ks[i];
    }
}

// ---------------- kv reduce: sum 32 partials -> kvb, ksum ----------------
__global__ __launch_bounds__(256) void kv_reduce(const float* __restrict__ kvp,
                                                 const float* __restrict__ ksp,
                                                 float* __restrict__ kvb,
                                                 float* __restrict__ ksum) {
    int tid = blockIdx.x * 256 + threadIdx.x;  // 0..262143
    int bh = tid >> 12, e = tid & 4095;
    float s = 0.0f;
#pragma unroll 8
    for (int c = 0; c < 32; c++) s += kvp[((size_t)(bh * 32 + c)) * 4096 + e];
    kvb[(size_t)bh * 4096 + e] = s;
    if (tid < 4096) {
        int bh2 = tid >> 6, dk = tid & 63;
        float t = 0.0f;
#pragma unroll 8
        for (int c = 0; c < 32; c++) t += ksp[((size_t)(bh2 * 32 + c)) * 64 + dk];
        ksum[tid] = t;
    }
}

// ---------------- attn; IN-PLACE over q ----------------
__global__ __launch_bounds__(256) void attn_kernel(unsigned short* qa,
                                                   const float* __restrict__ kv,
                                                   const float* __restrict__ ksum) {
    int bh = blockIdx.y;
    int b = bh >> 3, h = bh & 7;
    int nt = blockIdx.x;
    __shared__ float kvs[64 * 64];
    __shared__ float nrm[64];
    int t = threadIdx.x;
    for (int i = t; i < 4096; i += 256) kvs[i] = kv[(size_t)bh * 4096 + i];
    if (t < 64) nrm[t] = fmaxf(ksum[bh * 64 + t], 100.0f);
    __syncthreads();
    int n = nt * 256 + t;
    unsigned short* qp = qa + ((size_t)(b * 4096 + n)) * 512 + h * 64;
    float qf[64];
#pragma unroll
    for (int i = 0; i < 64; i += 8) {
        v8s v = *(const v8s*)&qp[i];
#pragma unroll
        for (int j = 0; j < 8; j++) qf[i + j] = b2f((unsigned short)v[j]);
    }
    float denom = 0.0f;
#pragma unroll
    for (int d = 0; d < 64; d++) denom += qf[d] * nrm[d];
    denom = fmaxf(denom, 100.0f);
    float inv = 1.0f / denom;
#pragma unroll
    for (int dv = 0; dv < 64; dv += 16) {
        float o[16] = {};
        for (int dk = 0; dk < 64; dk++) {
            float q = qf[dk];
#pragma unroll
            for (int i = 0; i < 16; i++) o[i] += q * kvs[dk * 64 + dv + i];
        }
#pragma unroll
        for (int i = 0; i < 16; i++) qp[dv + i] = f2b(o[i] * inv);
    }
}

// ---------------- depthwise conv 7x7 + GELU + BN stats; column-sliding ----------
__global__ __launch_bounds__(256) void dwconv7_gelu(const unsigned short* __restrict__ in,
                                                    const float* __restrict__ w,
                                                    const float* __restrict__ bias,
                                                    unsigned short* __restrict__ out,
                                                    float* __restrict__ bn_sum,
                                                    float* __restrict__ bn_sumsq) {
    int bc = blockIdx.x;
    int c = bc & 511;
    __shared__ float img[70 * 72];
    __shared__ float wsm[49];
    __shared__ float r1[4], r2[4];
    int t = threadIdx.x;
    int tx = t & 63, ty = t >> 6;
    for (int i = t; i < 70 * 72; i += 256) img[i] = 0.0f;
    if (t < 49) wsm[t] = w[c * 49 + t];
    __syncthreads();
    const unsigned short* src = in + (size_t)bc * 4096;
    for (int p = t; p < 4096; p += 256)
        img[((p >> 6) + 3) * 72 + (p & 63) + 3] = b2f(src[p]);
    __syncthreads();
    float wt[49];
#pragma unroll
    for (int i = 0; i < 49; i++) wt[i] = wsm[i];
    float bv = bias[c];
    float acc[16];
#pragma unroll
    for (int i = 0; i < 16; i++) acc[i] = bv;
    int h0 = ty * 16;
#pragma unroll
    for (int rr = 0; rr < 22; rr++) {
        float v[7];
#pragma unroll
        for (int kw = 0; kw < 7; kw++) v[kw] = img[(h0 + rr) * 72 + tx + kw];
#pragma unroll
        for (int kh = 0; kh < 7; kh++) {
            int o = rr - kh;
            if (o >= 0 && o <= 15) {
                float dot = v[0] * wt[kh * 7];
#pragma unroll
                for (int kw = 1; kw < 7; kw++) dot += v[kw] * wt[kh * 7 + kw];
                acc[o] += dot;
            }
        }
    }
    float s = 0.0f, s2 = 0.0f;
    unsigned short* dst = out + (size_t)bc * 4096;
#pragma unroll
    for (int i = 0; i < 16; i++) {
        float a = acc[i];
        float ge = 0.5f * a * (1.0f + erff(a * 0.70710678118f));
        dst[(h0 + i) * 64 + tx] = f2b(ge);
        s += ge;
        s2 += ge * ge;
    }
    for (int o = 32; o > 0; o >>= 1) {
        s += __shfl_down(s, o);
        s2 += __shfl_down(s2, o);
    }
    int lane = t & 63;
    if (lane == 0) { r1[ty] = s; r2[ty] = s2; }
    __syncthreads();
    if (t == 0) {
        atomicAdd(&bn_sum[c], r1[0] + r1[1] + r1[2] + r1[3]);
        atomicAdd(&bn_sumsq[c], r2[0] + r2[1] + r2[2] + r2[3]);
    }
}

__global__ void bn_finalize(const float* __restrict__ s, const float* __restrict__ s2,
                            const float* __restrict__ g, const float* __restrict__ b,
                            float2* __restrict__ ab) {
    int c = blockIdx.x * blockDim.x + threadIdx.x;
    if (c >= 512) return;
    float m = s[c] * (1.0f / 32768.0f);
    float var = s2[c] * (1.0f / 32768.0f) - m * m;
    float inv = rsqrtf(var + 1e-5f);
    float sc = g[c] * inv;
    ab[c] = make_float2(sc, b[c] - m * sc);
}

// ---------------- depthwise conv 7x7 with BN affine on load; column-sliding -------------------
__global__ __launch_bounds__(256) void dwconv7_bn(const unsigned short* __restrict__ in,
                                                  const float2* __restrict__ bnab,
                                                  const float* __restrict__ w,
                                                  const float* __restrict__ bias,
                                                  unsigned short* __restrict__ out) {
    int bc = blockIdx.x;
    int c = bc & 511;
    __shared__ float img[70 * 72];
    __shared__ float wsm[49];
    int t = threadIdx.x;
    int tx = t & 63, ty = t >> 6;
    for (int i = t; i < 70 * 72; i += 256) img[i] = 0.0f;
    if (t < 49) wsm[t] = w[c * 49 + t];
    __syncthreads();
    float2 ab = bnab[c];
    const unsigned short* src = in + (size_t)bc * 4096;
    for (int p = t; p < 4096; p += 256)
        img[((p >> 6) + 3) * 72 + (p & 63) + 3] = b2f(src[p]) * ab.x + ab.y;
    __syncthreads();
    float wt[49];
#pragma unroll
    for (int i = 0; i < 49; i++) wt[i] = wsm[i];
    float bv = bias[c];
    float acc[16];
#pragma unroll
    for (int i = 0; i < 16; i++) acc[i] = bv;
    int h0 = ty * 16;
#pragma unroll
    for (int rr = 0; rr < 22; rr++) {
        float v[7];
#pragma unroll
        for (int kw = 0; kw < 7; kw++) v[kw] = img[(h0 + rr) * 72 + tx + kw];
#pragma unroll
        for (int kh = 0; kh < 7; kh++) {
            int o = rr - kh;
            if (o >= 0 && o <= 15) {
                float dot = v[0] * wt[kh * 7];
#pragma unroll
                for (int kw = 1; kw < 7; kw++) dot += v[kw] * wt[kh * 7 + kw];
                acc[o] += dot;
            }
        }
    }
    unsigned short* dst = out + (size_t)bc * 4096;
#pragma unroll
    for (int i = 0; i < 16; i++)
        dst[(h0 + i) * 64 + tx] = f2b(acc[i]);
}

// ---------------- final: out = x(f32) + attn(bf16) + y2^T(bf16) -> f32 ----------------
__global__ __launch_bounds__(256) void final_add(const float* __restrict__ x,
                                                 const unsigned short* __restrict__ attn,
                                                 const unsigned short* __restrict__ y2,
                                                 float* __restrict__ out) {
    __shared__ unsigned short tile[32][33];
    int b = blockIdx.z;
    int c0 = blockIdx.x * 32, n0 = blockIdx.y * 32;
    int tx = threadIdx.x, ty = threadIdx.y;
    for (int j = 0; j < 32; j += 8)
        tile[ty + j][tx] = y2[((size_t)(b * 512 + c0 + ty + j)) * 4096 + n0 + tx];
    __syncthreads();
    for (int j = 0; j < 32; j += 8) {
        int n = n0 + ty + j, cc = c0 + tx;
        size_t idx = ((size_t)(b * 4096 + n)) * 512 + cc;
        out[idx] = x[idx] + b2f(attn[idx]) + b2f(tile[tx][ty + j]);
    }
}

// ------------------------------------------------------------------------------------------------
extern "C" void kernel_launch(void* const* d_in, const int* in_sizes, int n_in,
                              void* d_out, int out_size, void* d_ws, size_t ws_size,
                              hipStream_t stream) {
    const float* x     = (const float*)d_in[0];
    const float* qkv_w = (const float*)d_in[1];
    const float* qkv_b = (const float*)d_in[2];
    const float* out_w = (const float*)d_in[3];
    const float* out_b = (const float*)d_in[4];
    const float* pre_g = (const float*)d_in[5];
    const float* pre_b = (const float*)d_in[6];
    const float* lcm_g = (const float*)d_in[7];
    const float* lcm_b = (const float*)d_in[8];
    const float* ci_w  = (const float*)d_in[9];
    const float* ci_b  = (const float*)d_in[10];
    const float* bn_g  = (const float*)d_in[11];
    const float* bn_b  = (const float*)d_in[12];
    const float* co_w  = (const float*)d_in[13];
    const float* co_b  = (const float*)d_in[14];

    char* ws = (char*)d_ws;
    const size_t SLOT = 33554432;  // 32768*512*2 bytes (bf16)
    unsigned short* S0 = (unsigned short*)(ws);               // q -> attn -> xi -> y2
    unsigned short* S1 = (unsigned short*)(ws + SLOT);        // k -> attn_out(bf16)
    unsigned short* S2 = (unsigned short*)(ws + 2 * SLOT);    // v -> t -> y
    const size_t MISC = 3 * SLOT;                             // 96MB
    unsigned short* wT1 = (unsigned short*)(ws + MISC);                 // 1.5MB bf16
    unsigned short* wT2 = (unsigned short*)(ws + MISC + 1572864);       // 0.5MB bf16
    float* kvb          = (float*)(ws + MISC + 2097152);                // 1MB
    float* ksum         = (float*)(ws + MISC + 2097152 + 1048576);      // 16KB
    float* bn_sum       = (float*)(ws + MISC + 2097152 + 1048576 + 16384);        // 2KB
    float* bn_sumsq     = (float*)(ws + MISC + 2097152 + 1048576 + 16384 + 2048); // 2KB
    float2* bnab        = (float2*)(ws + MISC + 3166208);               // 4KB
    float* ksp          = (float*)(ws + MISC + 3170304);                // 512KB
    float* outp         = (float*)d_out;

    // d_out doubles as scratch before final_add fully overwrites it:
    unsigned short* normed = (unsigned short*)d_out;                    // 32MB bf16
    float* kvp             = (float*)((char*)d_out + SLOT);             // 32MB fp32 partials

    dim3 tb(32, 8);
    transpose_f2b<<<dim3(48, 16), tb, 0, stream>>>(qkv_w, wT1, 512, 1536);
    transpose_f2b<<<dim3(16, 16), tb, 0, stream>>>(out_w, wT2, 512, 512);
    zero_fill<<<4, 256, 0, stream>>>(bn_sum, 1024);  // bn_sum + bn_sumsq
    // LN1 once: x -> normed (bf16, in d_out scratch)
    ln_apply<<<32768, 256, 0, stream>>>(x, pre_g, pre_b, normed);
    // GEMM1: q->S0, k->S1, v->S2; relu on q,k
    gemm_qkv<<<dim3(12, 256), 256, 0, stream>>>(normed, wT1, qkv_b, S0, S1, S2);
    // kv partials (no atomics) + reduce
    kv_part<<<dim3(64, 32), 256, 0, stream>>>(S1, S2, kvp, ksp);
    kv_reduce<<<1024, 256, 0, stream>>>(kvp, ksp, kvb, ksum);
    attn_kernel<<<dim3(16, 64), 256, 0, stream>>>(S0, kvb, ksum);
    gemm_bf16<<<dim3(4, 256), 256, 0, stream>>>(S0, wT2, out_b, S1);
    ln_bf16_kernel<<<32768, 256, 0, stream>>>(S1, lcm_g, lcm_b, S2);
    transpose_bf16<<<dim3(16, 128, 8), tb, 0, stream>>>(S2, S0, 4096, 512);
    dwconv7_gelu<<<4096, 256, 0, stream>>>(S0, ci_w, ci_b, S2, bn_sum, bn_sumsq);
    bn_finalize<<<2, 256, 0, stream>>>(bn_sum, bn_sumsq, bn_g, bn_b, bnab);
    dwconv7_bn<<<4096, 256, 0, stream>>>(S2, bnab, co_w, co_b, S0);
    final_add<<<dim3(16, 128, 8), tb, 0, stream>>>(x, S1, S0, outp);
}

// Round 6
// 547.765 us; speedup vs baseline: 1.6432x; 1.0299x over previous
//
#include <hip/hip_runtime.h>
#include <math.h>

typedef short v8s __attribute__((ext_vector_type(8)));
typedef short v4s __attribute__((ext_vector_type(4)));
typedef float v4f __attribute__((ext_vector_type(4)));

__device__ __forceinline__ float b2f(unsigned short u) {
    return __uint_as_float(((unsigned)u) << 16);
}
__device__ __forceinline__ unsigned short f2b(float f) {
    unsigned u = __float_as_uint(f);
    unsigned r = (u + 0x7FFF + ((u >> 16) & 1)) >> 16;
    return (unsigned short)r;
}

// async global->LDS, 16B per lane; lds dest is wave-uniform base + lane*16
__device__ __forceinline__ void gl_lds16(const unsigned short* g, unsigned short* l) {
    __builtin_amdgcn_global_load_lds(
        (const __attribute__((address_space(1))) void*)g,
        (__attribute__((address_space(3))) void*)l,
        16, 0, 0);
}

// ---------------- zero fill ----------------
__global__ __launch_bounds__(256) void zero_fill(float* __restrict__ p, int n) {
    int i = blockIdx.x * 256 + threadIdx.x;
    if (i < n) p[i] = 0.0f;
}

// ---------------- LN1 fused: fp32 x -> bf16 normed ----------------
__global__ __launch_bounds__(256) void ln_apply(const float* __restrict__ x,
                                                const float* __restrict__ g,
                                                const float* __restrict__ bt,
                                                unsigned short* __restrict__ out) {
    size_t row = blockIdx.x;
    const float* p = x + row * 512;
    int t = threadIdx.x;
    float v0 = p[t];
    float v1 = p[t + 256];
    float s = v0 + v1, s2 = v0 * v0 + v1 * v1;
    for (int o = 32; o > 0; o >>= 1) {
        s += __shfl_down(s, o);
        s2 += __shfl_down(s2, o);
    }
    __shared__ float rs[4], rq[4];
    int wave = t >> 6, lane = t & 63;
    if (lane == 0) { rs[wave] = s; rq[wave] = s2; }
    __syncthreads();
    float ts = rs[0] + rs[1] + rs[2] + rs[3];
    float tq = rq[0] + rq[1] + rq[2] + rq[3];
    float mean = ts * (1.0f / 512.0f);
    float var = tq * (1.0f / 512.0f) - mean * mean;
    float inv = rsqrtf(var + 1e-5f);
    unsigned short* o0 = out + row * 512;
    o0[t]       = f2b((v0 - mean) * inv * g[t]       + bt[t]);
    o0[t + 256] = f2b((v1 - mean) * inv * g[t + 256] + bt[t + 256]);
}

// ---------------- LayerNorm: bf16 in -> bf16 out, fp32 gamma/beta (LN2) ----------------
__global__ __launch_bounds__(256) void ln_bf16_kernel(const unsigned short* __restrict__ in,
                                                      const float* __restrict__ g,
                                                      const float* __restrict__ bt,
                                                      unsigned short* __restrict__ out) {
    size_t row = blockIdx.x;
    const unsigned short* p = in + row * 512;
    int t = threadIdx.x;
    float v0 = b2f(p[t]);
    float v1 = b2f(p[t + 256]);
    float s = v0 + v1, s2 = v0 * v0 + v1 * v1;
    for (int o = 32; o > 0; o >>= 1) {
        s += __shfl_down(s, o);
        s2 += __shfl_down(s2, o);
    }
    __shared__ float rs[4], rq[4];
    int wave = t >> 6, lane = t & 63;
    if (lane == 0) { rs[wave] = s; rq[wave] = s2; }
    __syncthreads();
    float ts = rs[0] + rs[1] + rs[2] + rs[3];
    float tq = rq[0] + rq[1] + rq[2] + rq[3];
    float mean = ts * (1.0f / 512.0f);
    float var = tq * (1.0f / 512.0f) - mean * mean;
    float inv = rsqrtf(var + 1e-5f);
    unsigned short* o0 = out + row * 512;
    o0[t]       = f2b((v0 - mean) * inv * g[t]       + bt[t]);
    o0[t + 256] = f2b((v1 - mean) * inv * g[t + 256] + bt[t + 256]);
}

// ---------------- weight transpose + fp32->bf16 ----------------
__global__ __launch_bounds__(256) void transpose_f2b(const float* __restrict__ in,
                                                     unsigned short* __restrict__ out,
                                                     int R, int C) {
    __shared__ unsigned short tile[32][33];
    int c0 = blockIdx.x * 32, r0 = blockIdx.y * 32;
    int tx = threadIdx.x, ty = threadIdx.y;
    for (int j = 0; j < 32; j += 8)
        tile[ty + j][tx] = f2b(in[(size_t)(r0 + ty + j) * C + c0 + tx]);
    __syncthreads();
    for (int j = 0; j < 32; j += 8)
        out[(size_t)(c0 + ty + j) * R + r0 + tx] = tile[tx][ty + j];
}

// ---------------- tiled bf16 transpose ----------------
__global__ __launch_bounds__(256) void transpose_bf16(const unsigned short* __restrict__ in,
                                                      unsigned short* __restrict__ out,
                                                      int R, int C) {
    __shared__ unsigned short tile[32][33];
    size_t boff = (size_t)blockIdx.z * R * C;
    int c0 = blockIdx.x * 32, r0 = blockIdx.y * 32;
    int tx = threadIdx.x, ty = threadIdx.y;
    for (int j = 0; j < 32; j += 8)
        tile[ty + j][tx] = in[boff + (size_t)(r0 + ty + j) * C + c0 + tx];
    __syncthreads();
    for (int j = 0; j < 32; j += 8)
        out[boff + (size_t)(c0 + ty + j) * R + r0 + tx] = tile[tx][ty + j];
}

// ---------------- GEMM1 (m97 structure): normed A * Bt -> q/k/v slots, relu on q,k -------------
__global__ __launch_bounds__(256) void gemm_qkv(const unsigned short* __restrict__ A,
                                                const unsigned short* __restrict__ Bt,
                                                const float* __restrict__ bias,
                                                unsigned short* __restrict__ oq,
                                                unsigned short* __restrict__ ok,
                                                unsigned short* __restrict__ ov) {
    __shared__ __align__(16) unsigned short As[128 * 32];
    __shared__ __align__(16) unsigned short Bs[128 * 32];
    int t = threadIdx.x;
    int wave = t >> 6, lane = t & 63;
    int wm = (wave >> 1) * 64, wn = (wave & 1) * 64;
    int m0 = blockIdx.y * 128, n0 = blockIdx.x * 128;
    int mrow = lane & 15, kq = (lane >> 4) * 8;
    v4f acc[4][4] = {};
    // staging: tile = 512 x 16B chunks; wave w covers chunks [w*128, w*128+128)
    int ch0 = wave * 128 + lane;
    int ch1 = ch0 + 64;
    int ra = ch0 >> 2, ca = (ch0 & 3) * 8;
    int rb = ch1 >> 2, cb = (ch1 & 3) * 8;
    unsigned short* ldsA0 = &As[wave * 1024];
    unsigned short* ldsA1 = &As[wave * 1024 + 512];
    unsigned short* ldsB0 = &Bs[wave * 1024];
    unsigned short* ldsB1 = &Bs[wave * 1024 + 512];
    const unsigned short* Ab = A + (size_t)m0 * 512;
    const unsigned short* Bb = Bt + (size_t)n0 * 512;
    for (int k0 = 0; k0 < 512; k0 += 32) {
        __syncthreads();
        gl_lds16(&Ab[(size_t)ra * 512 + k0 + ca], ldsA0);
        gl_lds16(&Ab[(size_t)rb * 512 + k0 + cb], ldsA1);
        gl_lds16(&Bb[(size_t)ra * 512 + k0 + ca], ldsB0);
        gl_lds16(&Bb[(size_t)rb * 512 + k0 + cb], ldsB1);
        __syncthreads();
        v8s af[4], bf[4];
#pragma unroll
        for (int i = 0; i < 4; i++) af[i] = *(v8s*)&As[(wm + i * 16 + mrow) * 32 + kq];
#pragma unroll
        for (int i = 0; i < 4; i++) bf[i] = *(v8s*)&Bs[(wn + i * 16 + mrow) * 32 + kq];
#pragma unroll
        for (int i = 0; i < 4; i++)
#pragma unroll
            for (int j = 0; j < 4; j++)
                acc[i][j] = __builtin_amdgcn_mfma_f32_16x16x32_bf16(af[i], bf[j], acc[i][j], 0, 0, 0);
    }
#pragma unroll
    for (int j = 0; j < 4; j++) {
        int col = n0 + wn + j * 16 + mrow;
        float bv = bias[col];
        int seg = col >> 9;
        int c = col & 511;
        unsigned short* base = (seg == 0) ? oq : ((seg == 1) ? ok : ov);
        bool doRelu = col < 1024;
#pragma unroll
        for (int i = 0; i < 4; i++) {
            int row = m0 + wm + i * 16 + (lane >> 4) * 4;
#pragma unroll
            for (int r = 0; r < 4; r++) {
                float v = acc[i][j][r] + bv;
                if (doRelu) v = fmaxf(v, 0.0f);
                base[(size_t)(row + r) * 512 + c] = f2b(v);
            }
        }
    }
}

// ---------------- GEMM2 (m97 structure): bf16 A * Bt + fp32 bias -> bf16 out ----------------
__global__ __launch_bounds__(256) void gemm_bf16(const unsigned short* __restrict__ A,
                                                 const unsigned short* __restrict__ Bt,
                                                 const float* __restrict__ bias,
                                                 unsigned short* __restrict__ outp) {
    __shared__ __align__(16) unsigned short As[128 * 32];
    __shared__ __align__(16) unsigned short Bs[128 * 32];
    int t = threadIdx.x;
    int wave = t >> 6, lane = t & 63;
    int wm = (wave >> 1) * 64, wn = (wave & 1) * 64;
    int m0 = blockIdx.y * 128, n0 = blockIdx.x * 128;
    int mrow = lane & 15, kq = (lane >> 4) * 8;
    v4f acc[4][4] = {};
    int ch0 = wave * 128 + lane;
    int ch1 = ch0 + 64;
    int ra = ch0 >> 2, ca = (ch0 & 3) * 8;
    int rb = ch1 >> 2, cb = (ch1 & 3) * 8;
    unsigned short* ldsA0 = &As[wave * 1024];
    unsigned short* ldsA1 = &As[wave * 1024 + 512];
    unsigned short* ldsB0 = &Bs[wave * 1024];
    unsigned short* ldsB1 = &Bs[wave * 1024 + 512];
    const unsigned short* Ab = A + (size_t)m0 * 512;
    const unsigned short* Bb = Bt + (size_t)n0 * 512;
    for (int k0 = 0; k0 < 512; k0 += 32) {
        __syncthreads();
        gl_lds16(&Ab[(size_t)ra * 512 + k0 + ca], ldsA0);
        gl_lds16(&Ab[(size_t)rb * 512 + k0 + cb], ldsA1);
        gl_lds16(&Bb[(size_t)ra * 512 + k0 + ca], ldsB0);
        gl_lds16(&Bb[(size_t)rb * 512 + k0 + cb], ldsB1);
        __syncthreads();
        v8s af[4], bf[4];
#pragma unroll
        for (int i = 0; i < 4; i++) af[i] = *(v8s*)&As[(wm + i * 16 + mrow) * 32 + kq];
#pragma unroll
        for (int i = 0; i < 4; i++) bf[i] = *(v8s*)&Bs[(wn + i * 16 + mrow) * 32 + kq];
#pragma unroll
        for (int i = 0; i < 4; i++)
#pragma unroll
            for (int j = 0; j < 4; j++)
                acc[i][j] = __builtin_amdgcn_mfma_f32_16x16x32_bf16(af[i], bf[j], acc[i][j], 0, 0, 0);
    }
#pragma unroll
    for (int j = 0; j < 4; j++) {
        int col = n0 + wn + j * 16 + mrow;
        float bv = bias[col];
#pragma unroll
        for (int i = 0; i < 4; i++) {
            int row = m0 + wm + i * 16 + (lane >> 4) * 4;
#pragma unroll
            for (int r = 0; r < 4; r++)
                outp[(size_t)(row + r) * 512 + col] = f2b(acc[i][j][r] + bv);
        }
    }
}

// ---------------- kv partials: per (bh, chunk of 128 rows), no atomics ----------------
__global__ __launch_bounds__(256) void kv_part(const unsigned short* __restrict__ kbuf,
                                               const unsigned short* __restrict__ vbuf,
                                               float* __restrict__ kvp,
                                               float* __restrict__ ksp) {
    int bh = blockIdx.x;   // 0..63
    int b = bh >> 3, h = bh & 7;
    int nc = blockIdx.y;   // 0..31
    __shared__ __align__(16) unsigned short kb[64 * 64];
    __shared__ __align__(16) unsigned short vb[64 * 64];
    int t = threadIdx.x;
    int dk0 = (t >> 4) * 4;
    int dv0 = (t & 15) * 4;
    float acc[4][4] = {};
    float ks[4] = {};
    int lr = t >> 2, lc = (t & 3) * 16;
    for (int n0 = nc * 128; n0 < nc * 128 + 128; n0 += 64) {
        __syncthreads();
        size_t base = ((size_t)(b * 4096 + n0 + lr)) * 512 + h * 64;
        *(v8s*)&kb[lr * 64 + lc]     = *(const v8s*)&kbuf[base + lc];
        *(v8s*)&kb[lr * 64 + lc + 8] = *(const v8s*)&kbuf[base + lc + 8];
        *(v8s*)&vb[lr * 64 + lc]     = *(const v8s*)&vbuf[base + lc];
        *(v8s*)&vb[lr * 64 + lc + 8] = *(const v8s*)&vbuf[base + lc + 8];
        __syncthreads();
#pragma unroll 4
        for (int nn = 0; nn < 64; nn++) {
            v4s kr = *(const v4s*)&kb[nn * 64 + dk0];
            v4s vr = *(const v4s*)&vb[nn * 64 + dv0];
            float kf[4], vf[4];
#pragma unroll
            for (int i = 0; i < 4; i++) { kf[i] = b2f((unsigned short)kr[i]); vf[i] = b2f((unsigned short)vr[i]); }
#pragma unroll
            for (int i = 0; i < 4; i++) {
#pragma unroll
                for (int j = 0; j < 4; j++) acc[i][j] += kf[i] * vf[j];
            }
            if ((t & 15) == 0) {
#pragma unroll
                for (int i = 0; i < 4; i++) ks[i] += kf[i];
            }
        }
    }
    float* dst = kvp + ((size_t)(bh * 32 + nc)) * 4096;
#pragma unroll
    for (int i = 0; i < 4; i++)
        *(float4*)&dst[(dk0 + i) * 64 + dv0] = make_float4(acc[i][0], acc[i][1], acc[i][2], acc[i][3]);
    if ((t & 15) == 0) {
        float* kd = ksp + ((size_t)(bh * 32 + nc)) * 64;
#pragma unroll
        for (int i = 0; i < 4; i++) kd[dk0 + i] = ks[i];
    }
}

// ---------------- kv reduce: sum 32 partials -> kvb, ksum ----------------
__global__ __launch_bounds__(256) void kv_reduce(const float* __restrict__ kvp,
                                                 const float* __restrict__ ksp,
                                                 float* __restrict__ kvb,
                                                 float* __restrict__ ksum) {
    int tid = blockIdx.x * 256 + threadIdx.x;
    int bh = tid >> 12, e = tid & 4095;
    float s = 0.0f;
#pragma unroll 8
    for (int c = 0; c < 32; c++) s += kvp[((size_t)(bh * 32 + c)) * 4096 + e];
    kvb[(size_t)bh * 4096 + e] = s;
    if (tid < 4096) {
        int bh2 = tid >> 6, dk = tid & 63;
        float t = 0.0f;
#pragma unroll 8
        for (int c = 0; c < 32; c++) t += ksp[((size_t)(bh2 * 32 + c)) * 64 + dk];
        ksum[tid] = t;
    }
}

// ---------------- attn; IN-PLACE over q ----------------
__global__ __launch_bounds__(256) void attn_kernel(unsigned short* qa,
                                                   const float* __restrict__ kv,
                                                   const float* __restrict__ ksum) {
    int bh = blockIdx.y;
    int b = bh >> 3, h = bh & 7;
    int nt = blockIdx.x;
    __shared__ float kvs[64 * 64];
    __shared__ float nrm[64];
    int t = threadIdx.x;
    for (int i = t; i < 4096; i += 256) kvs[i] = kv[(size_t)bh * 4096 + i];
    if (t < 64) nrm[t] = fmaxf(ksum[bh * 64 + t], 100.0f);
    __syncthreads();
    int n = nt * 256 + t;
    unsigned short* qp = qa + ((size_t)(b * 4096 + n)) * 512 + h * 64;
    float qf[64];
#pragma unroll
    for (int i = 0; i < 64; i += 8) {
        v8s v = *(const v8s*)&qp[i];
#pragma unroll
        for (int j = 0; j < 8; j++) qf[i + j] = b2f((unsigned short)v[j]);
    }
    float denom = 0.0f;
#pragma unroll
    for (int d = 0; d < 64; d++) denom += qf[d] * nrm[d];
    denom = fmaxf(denom, 100.0f);
    float inv = 1.0f / denom;
#pragma unroll
    for (int dv = 0; dv < 64; dv += 16) {
        float o[16] = {};
        for (int dk = 0; dk < 64; dk++) {
            float q = qf[dk];
#pragma unroll
            for (int i = 0; i < 16; i++) o[i] += q * kvs[dk * 64 + dv + i];
        }
#pragma unroll
        for (int i = 0; i < 16; i++) qp[dv + i] = f2b(o[i] * inv);
    }
}

// ---------------- depthwise conv 7x7 + GELU + BN stats; column-sliding ----------
__global__ __launch_bounds__(256) void dwconv7_gelu(const unsigned short* __restrict__ in,
                                                    const float* __restrict__ w,
                                                    const float* __restrict__ bias,
                                                    unsigned short* __restrict__ out,
                                                    float* __restrict__ bn_sum,
                                                    float* __restrict__ bn_sumsq) {
    int bc = blockIdx.x;
    int c = bc & 511;
    __shared__ float img[70 * 72];
    __shared__ float wsm[49];
    __shared__ float r1[4], r2[4];
    int t = threadIdx.x;
    int tx = t & 63, ty = t >> 6;
    for (int i = t; i < 70 * 72; i += 256) img[i] = 0.0f;
    if (t < 49) wsm[t] = w[c * 49 + t];
    __syncthreads();
    const unsigned short* src = in + (size_t)bc * 4096;
    for (int p = t; p < 4096; p += 256)
        img[((p >> 6) + 3) * 72 + (p & 63) + 3] = b2f(src[p]);
    __syncthreads();
    float wt[49];
#pragma unroll
    for (int i = 0; i < 49; i++) wt[i] = wsm[i];
    float bv = bias[c];
    float acc[16];
#pragma unroll
    for (int i = 0; i < 16; i++) acc[i] = bv;
    int h0 = ty * 16;
#pragma unroll
    for (int rr = 0; rr < 22; rr++) {
        float v[7];
#pragma unroll
        for (int kw = 0; kw < 7; kw++) v[kw] = img[(h0 + rr) * 72 + tx + kw];
#pragma unroll
        for (int kh = 0; kh < 7; kh++) {
            int o = rr - kh;
            if (o >= 0 && o <= 15) {
                float dot = v[0] * wt[kh * 7];
#pragma unroll
                for (int kw = 1; kw < 7; kw++) dot += v[kw] * wt[kh * 7 + kw];
                acc[o] += dot;
            }
        }
    }
    float s = 0.0f, s2 = 0.0f;
    unsigned short* dst = out + (size_t)bc * 4096;
#pragma unroll
    for (int i = 0; i < 16; i++) {
        float a = acc[i];
        float ge = 0.5f * a * (1.0f + erff(a * 0.70710678118f));
        dst[(h0 + i) * 64 + tx] = f2b(ge);
        s += ge;
        s2 += ge * ge;
    }
    for (int o = 32; o > 0; o >>= 1) {
        s += __shfl_down(s, o);
        s2 += __shfl_down(s2, o);
    }
    int lane = t & 63;
    if (lane == 0) { r1[ty] = s; r2[ty] = s2; }
    __syncthreads();
    if (t == 0) {
        atomicAdd(&bn_sum[c], r1[0] + r1[1] + r1[2] + r1[3]);
        atomicAdd(&bn_sumsq[c], r2[0] + r2[1] + r2[2] + r2[3]);
    }
}

__global__ void bn_finalize(const float* __restrict__ s, const float* __restrict__ s2,
                            const float* __restrict__ g, const float* __restrict__ b,
                            float2* __restrict__ ab) {
    int c = blockIdx.x * blockDim.x + threadIdx.x;
    if (c >= 512) return;
    float m = s[c] * (1.0f / 32768.0f);
    float var = s2[c] * (1.0f / 32768.0f) - m * m;
    float inv = rsqrtf(var + 1e-5f);
    float sc = g[c] * inv;
    ab[c] = make_float2(sc, b[c] - m * sc);
}

// ---------------- depthwise conv 7x7 with BN affine on load; column-sliding -------------------
__global__ __launch_bounds__(256) void dwconv7_bn(const unsigned short* __restrict__ in,
                                                  const float2* __restrict__ bnab,
                                                  const float* __restrict__ w,
                                                  const float* __restrict__ bias,
                                                  unsigned short* __restrict__ out) {
    int bc = blockIdx.x;
    int c = bc & 511;
    __shared__ float img[70 * 72];
    __shared__ float wsm[49];
    int t = threadIdx.x;
    int tx = t & 63, ty = t >> 6;
    for (int i = t; i < 70 * 72; i += 256) img[i] = 0.0f;
    if (t < 49) wsm[t] = w[c * 49 + t];
    __syncthreads();
    float2 ab = bnab[c];
    const unsigned short* src = in + (size_t)bc * 4096;
    for (int p = t; p < 4096; p += 256)
        img[((p >> 6) + 3) * 72 + (p & 63) + 3] = b2f(src[p]) * ab.x + ab.y;
    __syncthreads();
    float wt[49];
#pragma unroll
    for (int i = 0; i < 49; i++) wt[i] = wsm[i];
    float bv = bias[c];
    float acc[16];
#pragma unroll
    for (int i = 0; i < 16; i++) acc[i] = bv;
    int h0 = ty * 16;
#pragma unroll
    for (int rr = 0; rr < 22; rr++) {
        float v[7];
#pragma unroll
        for (int kw = 0; kw < 7; kw++) v[kw] = img[(h0 + rr) * 72 + tx + kw];
#pragma unroll
        for (int kh = 0; kh < 7; kh++) {
            int o = rr - kh;
            if (o >= 0 && o <= 15) {
                float dot = v[0] * wt[kh * 7];
#pragma unroll
                for (int kw = 1; kw < 7; kw++) dot += v[kw] * wt[kh * 7 + kw];
                acc[o] += dot;
            }
        }
    }
    unsigned short* dst = out + (size_t)bc * 4096;
#pragma unroll
    for (int i = 0; i < 16; i++)
        dst[(h0 + i) * 64 + tx] = f2b(acc[i]);
}

// ---------------- final: out = x(f32) + attn(bf16) + y2^T(bf16) -> f32 ----------------
__global__ __launch_bounds__(256) void final_add(const float* __restrict__ x,
                                                 const unsigned short* __restrict__ attn,
                                                 const unsigned short* __restrict__ y2,
                                                 float* __restrict__ out) {
    __shared__ unsigned short tile[32][33];
    int b = blockIdx.z;
    int c0 = blockIdx.x * 32, n0 = blockIdx.y * 32;
    int tx = threadIdx.x, ty = threadIdx.y;
    for (int j = 0; j < 32; j += 8)
        tile[ty + j][tx] = y2[((size_t)(b * 512 + c0 + ty + j)) * 4096 + n0 + tx];
    __syncthreads();
    for (int j = 0; j < 32; j += 8) {
        int n = n0 + ty + j, cc = c0 + tx;
        size_t idx = ((size_t)(b * 4096 + n)) * 512 + cc;
        out[idx] = x[idx] + b2f(attn[idx]) + b2f(tile[tx][ty + j]);
    }
}

// ------------------------------------------------------------------------------------------------
extern "C" void kernel_launch(void* const* d_in, const int* in_sizes, int n_in,
                              void* d_out, int out_size, void* d_ws, size_t ws_size,
                              hipStream_t stream) {
    const float* x     = (const float*)d_in[0];
    const float* qkv_w = (const float*)d_in[1];
    const float* qkv_b = (const float*)d_in[2];
    const float* out_w = (const float*)d_in[3];
    const float* out_b = (const float*)d_in[4];
    const float* pre_g = (const float*)d_in[5];
    const float* pre_b = (const float*)d_in[6];
    const float* lcm_g = (const float*)d_in[7];
    const float* lcm_b = (const float*)d_in[8];
    const float* ci_w  = (const float*)d_in[9];
    const float* ci_b  = (const float*)d_in[10];
    const float* bn_g  = (const float*)d_in[11];
    const float* bn_b  = (const float*)d_in[12];
    const float* co_w  = (const float*)d_in[13];
    const float* co_b  = (const float*)d_in[14];

    char* ws = (char*)d_ws;
    const size_t SLOT = 33554432;  // 32768*512*2 bytes (bf16)
    unsigned short* S0 = (unsigned short*)(ws);               // q -> attn -> xi -> y2
    unsigned short* S1 = (unsigned short*)(ws + SLOT);        // k -> attn_out(bf16)
    unsigned short* S2 = (unsigned short*)(ws + 2 * SLOT);    // v -> t -> y
    const size_t MISC = 3 * SLOT;                             // 96MB
    unsigned short* wT1 = (unsigned short*)(ws + MISC);                 // 1.5MB bf16
    unsigned short* wT2 = (unsigned short*)(ws + MISC + 1572864);       // 0.5MB bf16
    float* kvb          = (float*)(ws + MISC + 2097152);                // 1MB
    float* ksum         = (float*)(ws + MISC + 2097152 + 1048576);      // 16KB
    float* bn_sum       = (float*)(ws + MISC + 2097152 + 1048576 + 16384);        // 2KB
    float* bn_sumsq     = (float*)(ws + MISC + 2097152 + 1048576 + 16384 + 2048); // 2KB
    float2* bnab        = (float2*)(ws + MISC + 3166208);               // 4KB
    float* ksp          = (float*)(ws + MISC + 3170304);                // 512KB
    float* outp         = (float*)d_out;

    // d_out doubles as scratch before final_add fully overwrites it:
    unsigned short* normed = (unsigned short*)d_out;                    // 32MB bf16
    float* kvp             = (float*)((char*)d_out + SLOT);             // 32MB fp32 partials

    dim3 tb(32, 8);
    transpose_f2b<<<dim3(48, 16), tb, 0, stream>>>(qkv_w, wT1, 512, 1536);
    transpose_f2b<<<dim3(16, 16), tb, 0, stream>>>(out_w, wT2, 512, 512);
    zero_fill<<<4, 256, 0, stream>>>(bn_sum, 1024);  // bn_sum + bn_sumsq
    ln_apply<<<32768, 256, 0, stream>>>(x, pre_g, pre_b, normed);
    gemm_qkv<<<dim3(12, 256), 256, 0, stream>>>(normed, wT1, qkv_b, S0, S1, S2);
    kv_part<<<dim3(64, 32), 256, 0, stream>>>(S1, S2, kvp, ksp);
    kv_reduce<<<1024, 256, 0, stream>>>(kvp, ksp, kvb, ksum);
    attn_kernel<<<dim3(16, 64), 256, 0, stream>>>(S0, kvb, ksum);
    gemm_bf16<<<dim3(4, 256), 256, 0, stream>>>(S0, wT2, out_b, S1);
    ln_bf16_kernel<<<32768, 256, 0, stream>>>(S1, lcm_g, lcm_b, S2);
    transpose_bf16<<<dim3(16, 128, 8), tb, 0, stream>>>(S2, S0, 4096, 512);
    dwconv7_gelu<<<4096, 256, 0, stream>>>(S0, ci_w, ci_b, S2, bn_sum, bn_sumsq);
    bn_finalize<<<2, 256, 0, stream>>>(bn_sum, bn_sumsq, bn_g, bn_b, bnab);
    dwconv7_bn<<<4096, 256, 0, stream>>>(S2, bnab, co_w, co_b, S0);
    final_add<<<dim3(16, 128, 8), tb, 0, stream>>>(x, S1, S0, outp);
}